// Round 6
// baseline (6289.688 us; speedup 1.0000x reference)
//
#include <hip/hip_runtime.h>
#include <math.h>
#include <stdint.h>

#define B 1024
#define H 512
#define E 256
#define L 128
#define LE (L*E)   // 32768

typedef _Float16 f16;
typedef _Float16 f16x8 __attribute__((ext_vector_type(8)));
typedef float f32x4 __attribute__((ext_vector_type(4)));
typedef const __attribute__((address_space(1))) uint32_t gu32;
typedef __attribute__((address_space(3))) uint32_t lu32;

// ---------------------------------------------------------------------------
// Persistent state in module device globals (round-1 lesson: d_ws unsafe).
// Everything rewritten every call -> deterministic graph replays.
// ---------------------------------------------------------------------------
__device__ __align__(16) f16 g_Xs[127*16*4*4096]; // X images [t][mt16][kt:4] 64x64
__device__ __align__(16) f16 g_Hs[2][16*8*4096];  // H images dbuf [mt16][kt:8] 64x64
__device__ __align__(16) f16 g_Ws[16*12*8192];    // gates W' [imgtile:16][kt:12] 128x64
__device__ __align__(16) f16 g_W1s[8*8192];       // W1' [kt:8] 128x64
__device__ __align__(16) f16 g_W2s[2*8192];       // W2' [kt:2] 128x64
__device__ __align__(16) f16 g_W3s[4*8192];       // W3' [nh:2][kt:2] 128x64
__device__ __align__(16) float g_bsum[2048];      // b_ih+b_hh, n=j*4+g order
__device__ unsigned int g_bar_count;
__device__ unsigned int g_bar_phase;

__device__ __forceinline__ float sigm(float x) { return 1.0f / (1.0f + expf(-x)); }

#define NBLK 256u

// Software grid barrier: one agent-scope atomic per block (G12), acq/rel
// fences give cross-XCD L2 visibility (G16). All 256 blocks are co-resident
// (1 block/CU exactly), so the counting barrier cannot deadlock.
__device__ __forceinline__ void grid_barrier(unsigned int target) {
    __syncthreads();   // drains each wave's vmcnt -> all stores in L2 before release
    if (threadIdx.x == 0) {
        unsigned int prev = __hip_atomic_fetch_add(&g_bar_count, 1u,
                              __ATOMIC_ACQ_REL, __HIP_MEMORY_SCOPE_AGENT);
        if (prev == NBLK - 1u) {
            __hip_atomic_store(&g_bar_count, 0u, __ATOMIC_RELAXED, __HIP_MEMORY_SCOPE_AGENT);
            __hip_atomic_store(&g_bar_phase, target, __ATOMIC_RELEASE, __HIP_MEMORY_SCOPE_AGENT);
        } else {
            while (__hip_atomic_load(&g_bar_phase, __ATOMIC_ACQUIRE,
                                     __HIP_MEMORY_SCOPE_AGENT) < target)
                __builtin_amdgcn_s_sleep(2);
        }
    }
    __syncthreads();
}

// ---------------------------------------------------------------------------
// conv_w: gates W' fp16 tile images (gate-interleaved n=j*4+g) + bias sums
// ---------------------------------------------------------------------------
__global__ __launch_bounds__(256) void conv_w(
    const float* __restrict__ W_ih, const float* __restrict__ W_hh,
    const float* __restrict__ b_ih, const float* __restrict__ b_hh)
{
    int gid = blockIdx.x*256 + threadIdx.x;   // 196608
    int kb  = gid & 7;
    int r1  = gid >> 3;
    int row = r1 & 127;
    int r2  = r1 >> 7;
    int kt  = r2 % 12;
    int nt  = r2 / 12;
    int n = nt*128 + row;
    int g = n & 3, j = n >> 2;
    int wrow = g*512 + j;
    int k = kt*64 + kb*8;
    const float* src = (k < 256) ? (W_ih + wrow*256 + k)
                                 : (W_hh + wrow*512 + (k - 256));
    f16x8 v;
    #pragma unroll
    for (int e = 0; e < 8; ++e) v[e] = (f16)src[e];
    char* dst = (char*)g_Ws + (size_t)(nt*12 + kt)*16384
              + row*128 + ((kb*16) ^ ((row & 7) << 4));
    *(f16x8*)dst = v;
    if (gid < 2048) {
        int gg = gid & 3, jj = gid >> 2;
        g_bsum[gid] = b_ih[gg*512 + jj] + b_hh[gg*512 + jj];
    }
}

// ---------------------------------------------------------------------------
// conv_mlp: W1/W2/W3 fp16 tile images
// ---------------------------------------------------------------------------
__global__ __launch_bounds__(256) void conv_mlp(
    const float* __restrict__ W1, const float* __restrict__ W2,
    const float* __restrict__ W3)
{
    int gid = blockIdx.x*256 + threadIdx.x;   // 14336
    if (gid < 8192) {                         // W1 (128,512) -> 8 tiles
        int s = gid;
        int kb = s & 7, row = (s >> 3) & 127, kt = s >> 10;
        const float* src = W1 + row*512 + kt*64 + kb*8;
        f16x8 v;
        #pragma unroll
        for (int e = 0; e < 8; ++e) v[e] = (f16)src[e];
        char* dst = (char*)g_W1s + (size_t)kt*16384
                  + row*128 + ((kb*16) ^ ((row & 7) << 4));
        *(f16x8*)dst = v;
    } else if (gid < 10240) {                 // W2 (128,128) -> 2 tiles
        int s = gid - 8192;
        int kb = s & 7, row = (s >> 3) & 127, kt = s >> 10;
        const float* src = W2 + row*128 + kt*64 + kb*8;
        f16x8 v;
        #pragma unroll
        for (int e = 0; e < 8; ++e) v[e] = (f16)src[e];
        char* dst = (char*)g_W2s + (size_t)kt*16384
                  + row*128 + ((kb*16) ^ ((row & 7) << 4));
        *(f16x8*)dst = v;
    } else if (gid < 14336) {                 // W3 (256,128) -> [nh:2][kt:2]
        int s = gid - 10240;
        int kb = s & 7, r256 = (s >> 3) & 255, kt = s >> 11;
        int nh = r256 >> 7, row = r256 & 127;
        const float* src = W3 + r256*128 + kt*64 + kb*8;
        f16x8 v;
        #pragma unroll
        for (int e = 0; e < 8; ++e) v[e] = (f16)src[e];
        char* dst = (char*)g_W3s + (size_t)(nh*2 + kt)*16384
                  + row*128 + ((kb*16) ^ ((row & 7) << 4));
        *(f16x8*)dst = v;
    }
}

// ---------------------------------------------------------------------------
// conv_x: X fp16 tile images; remapped so 32 consecutive lanes read 1 KB
// contiguous (round-5 fix: old mapping was 32B per 128KB stride, 1.75 TB/s)
// ---------------------------------------------------------------------------
__global__ __launch_bounds__(256) void conv_x(const float* __restrict__ padded)
{
    int gid = blockIdx.x*256 + threadIdx.x;   // 127*1024*32 = 4161536 exact
    int kq = gid & 31;            // 8-float chunk within row
    int b  = (gid >> 5) & 1023;
    int t  = gid >> 15;           // 0..126
    const float* src = padded + (size_t)b*LE + t*E + kq*8;
    float4 v0 = *(const float4*)src;
    float4 v1 = *(const float4*)(src + 4);
    f16x8 v;
    v[0]=(f16)v0.x; v[1]=(f16)v0.y; v[2]=(f16)v0.z; v[3]=(f16)v0.w;
    v[4]=(f16)v1.x; v[5]=(f16)v1.y; v[6]=(f16)v1.z; v[7]=(f16)v1.w;
    int kt = kq >> 3, kb = kq & 7;
    int row = b & 63, mt16 = b >> 6;
    char* dst = (char*)g_Xs + (size_t)((t*16 + mt16)*4 + kt)*8192
              + row*128 + ((kb*16) ^ ((row & 7) << 4));
    *(f16x8*)dst = v;
}

// ---------------------------------------------------------------------------
// init: H-image[0] <- hidden, out row 0 <- one-hot, barrier state reset
// ---------------------------------------------------------------------------
__global__ __launch_bounds__(256) void init_kernel(
    const float* __restrict__ hidden, float* __restrict__ out)
{
    int i = blockIdx.x * 256 + threadIdx.x;
    if (i == 0) { g_bar_count = 0u; g_bar_phase = 0u; }
    if (i < B*H) {
        float hv = hidden[i];
        int b = i >> 9, j = i & 511;
        int mt = b >> 6, row = b & 63, kt = j >> 6, kk = j & 63;
        char* dst = (char*)&g_Hs[0][0] + (size_t)(mt*8 + kt)*8192
                  + row*128 + ((kk*2) ^ ((row & 7) << 4));
        *(f16*)dst = (f16)hv;
    }
    if (i < B*E) {
        int b = i >> 8, e = i & 255;
        out[b*LE + e] = (e == 0) ? 1.0f : 0.0f;
    }
}

// ---------------------------------------------------------------------------
// step_all: ONE persistent kernel, 256 blocks x 256 threads (1 block/CU).
// Block (mt,nt) owns gates tile rows [mt*32,+32) x gate-cols [nt*256,+256).
// Gates W' lives in REGISTERS (96 f16x8/wave) for the whole call; c in regs.
// Per step: [duty: MLP(t)] -> stage H -> 24x(2 ds_read + 8 MFMA) -> epilogue
// (cell update, h-image store) with X(t+1) prefetch -> grid barrier.
// ---------------------------------------------------------------------------
__global__ __launch_bounds__(256, 1) void step_all(
    const float* __restrict__ b1, const float* __restrict__ b2,
    const float* __restrict__ b3, float* __restrict__ out)
{
    __shared__ __align__(16) char lds[106496];
    char* Alds = lds;                                  // 12 x 4096 (X:0..3, H:4..11)
    float (*Glds)[260] = (float (*)[260])(lds + 49152); // 32x260 f32
    char* hbuf = lds + 16384;   // MLP: aliases A H-part (dead then)
    char* Wmlp = lds + 32768;   // MLP: 64 KB, aliases A tail + Glds (dead then)
    char* z1b  = lds + 98304;
    char* z2b  = lds + 102400;

    const int tid  = threadIdx.x;
    const int lane = tid & 63;
    const int w    = tid >> 6;          // 0..3
    const int mt   = blockIdx.x >> 3;   // 0..31
    const int nt   = blockIdx.x & 7;    // 0..7
    const bool duty = (nt < 2);
    const int sblk = mt*2 + nt;         // MLP slice (rows sblk*16..+16) when duty

    const int l15 = lane & 15;
    const int klo = (lane >> 4) << 4;
    const int xr  = (l15 & 7) << 4;     // row-XOR for A (rows m*16+l15: &7==l15&7)

    // ---- gates B -> registers, persistent across all 127 steps ----
    f16x8 bw[24][4];
    {
        const char* gW = (const char*)g_Ws;
        const int itile = nt*2 + (w >> 1);
        const int brb = (w & 1) * 64;
        #pragma unroll
        for (int kt = 0; kt < 12; ++kt)
            #pragma unroll
            for (int kkl = 0; kkl < 2; ++kkl)
                #pragma unroll
                for (int n = 0; n < 4; ++n) {
                    int br = brb + n*16 + l15;
                    int kb = kkl*64 + klo;
                    bw[kt*2+kkl][n] = *(const f16x8*)(gW
                        + (size_t)(itile*12 + kt)*16384
                        + br*128 + (kb ^ ((br & 7) << 4)));
                }
    }
    float creg[8];
    #pragma unroll
    for (int i = 0; i < 8; ++i) creg[i] = 0.0f;

    const int jl  = tid & 63;
    const int blb = (tid >> 6) * 8;
    const float4 bsv = *(const float4*)&g_bsum[nt*256 + jl*4];

    float b1v[2] = {0,0}, b2v[2] = {0,0}, b3v[2][2] = {{0,0},{0,0}};
    if (duty) {
        #pragma unroll
        for (int n = 0; n < 2; ++n) {
            int col = w*32 + n*16 + l15;
            b1v[n] = b1[col]; b2v[n] = b2[col];
            b3v[0][n] = b3[col]; b3v[1][n] = b3[128 + col];
        }
    }

    // fused 3-layer MLP for rows [sblk*16,+16), writes out[:, step, :]
    auto do_mlp = [&](int step) {
        const char* hsrc = (const char*)&g_Hs[step & 1][0]
            + (size_t)((sblk >> 2)*8)*8192 + ((sblk & 3)*16)*128;
        #pragma unroll
        for (int it = 0; it < 4; ++it) {                 // h rows: 16 KB
            int s = tid + it*256;
            int kt = s >> 7, rb = s & 127;
            __builtin_amdgcn_global_load_lds((gu32*)(hsrc + (size_t)kt*8192 + rb*16),
                                             (lu32*)(hbuf + s*16), 16, 0, 0);
        }
        f32x4 m1[2];
        m1[0] = (f32x4){0,0,0,0}; m1[1] = (f32x4){0,0,0,0};
        #pragma unroll
        for (int half = 0; half < 2; ++half) {           // L1, K=512 in 2 halves
            __syncthreads();
            #pragma unroll
            for (int it = 0; it < 16; ++it) {            // 4 W1 tiles = 64 KB
                int s = tid + it*256;
                __builtin_amdgcn_global_load_lds(
                    (gu32*)((const char*)g_W1s + (size_t)half*65536 + s*16),
                    (lu32*)(Wmlp + s*16), 16, 0, 0);
            }
            __syncthreads();
            #pragma unroll
            for (int lt = 0; lt < 4; ++lt)
                #pragma unroll
                for (int kkl = 0; kkl < 2; ++kkl) {
                    int kb = kkl*64 + klo;
                    f16x8 a = *(const f16x8*)(hbuf + (half*4+lt)*2048
                                              + l15*128 + (kb ^ xr));
                    #pragma unroll
                    for (int n = 0; n < 2; ++n) {
                        int br = w*32 + n*16 + l15;
                        f16x8 bb = *(const f16x8*)(Wmlp + lt*16384
                                                   + br*128 + (kb ^ ((br&7)<<4)));
                        m1[n] = __builtin_amdgcn_mfma_f32_16x16x32_f16(a, bb, m1[n], 0, 0, 0);
                    }
                }
        }
        #pragma unroll
        for (int n = 0; n < 2; ++n)                      // z1 -> image
            #pragma unroll
            for (int i = 0; i < 4; ++i) {
                int row = ((lane>>4)<<2) + i;
                int col = w*32 + n*16 + l15;
                float v = fmaxf(m1[n][i] + b1v[n], 0.0f);
                *(f16*)(z1b + (col>>6)*2048 + row*128
                        + (((col&63)*2) ^ ((row&7)<<4))) = (f16)v;
            }
        __syncthreads();
        #pragma unroll
        for (int it = 0; it < 8; ++it) {                 // W2: 32 KB
            int s = tid + it*256;
            __builtin_amdgcn_global_load_lds((gu32*)((const char*)g_W2s + s*16),
                                             (lu32*)(Wmlp + s*16), 16, 0, 0);
        }
        __syncthreads();
        m1[0] = (f32x4){0,0,0,0}; m1[1] = (f32x4){0,0,0,0};
        #pragma unroll
        for (int kt = 0; kt < 2; ++kt)
            #pragma unroll
            for (int kkl = 0; kkl < 2; ++kkl) {
                int kb = kkl*64 + klo;
                f16x8 a = *(const f16x8*)(z1b + kt*2048 + l15*128 + (kb ^ xr));
                #pragma unroll
                for (int n = 0; n < 2; ++n) {
                    int br = w*32 + n*16 + l15;
                    f16x8 bb = *(const f16x8*)(Wmlp + kt*16384
                                               + br*128 + (kb ^ ((br&7)<<4)));
                    m1[n] = __builtin_amdgcn_mfma_f32_16x16x32_f16(a, bb, m1[n], 0, 0, 0);
                }
            }
        #pragma unroll
        for (int n = 0; n < 2; ++n)                      // z2 -> image
            #pragma unroll
            for (int i = 0; i < 4; ++i) {
                int row = ((lane>>4)<<2) + i;
                int col = w*32 + n*16 + l15;
                float v = fmaxf(m1[n][i] + b2v[n], 0.0f);
                *(f16*)(z2b + (col>>6)*2048 + row*128
                        + (((col&63)*2) ^ ((row&7)<<4))) = (f16)v;
            }
        __syncthreads();
        #pragma unroll
        for (int nh = 0; nh < 2; ++nh) {                 // L3, N=256
            #pragma unroll
            for (int it = 0; it < 8; ++it) {
                int s = tid + it*256;
                __builtin_amdgcn_global_load_lds(
                    (gu32*)((const char*)g_W3s + (size_t)nh*32768 + s*16),
                    (lu32*)(Wmlp + s*16), 16, 0, 0);
            }
            __syncthreads();
            m1[0] = (f32x4){0,0,0,0}; m1[1] = (f32x4){0,0,0,0};
            #pragma unroll
            for (int kt = 0; kt < 2; ++kt)
                #pragma unroll
                for (int kkl = 0; kkl < 2; ++kkl) {
                    int kb = kkl*64 + klo;
                    f16x8 a = *(const f16x8*)(z2b + kt*2048 + l15*128 + (kb ^ xr));
                    #pragma unroll
                    for (int n = 0; n < 2; ++n) {
                        int br = w*32 + n*16 + l15;
                        f16x8 bb = *(const f16x8*)(Wmlp + kt*16384
                                                   + br*128 + (kb ^ ((br&7)<<4)));
                        m1[n] = __builtin_amdgcn_mfma_f32_16x16x32_f16(a, bb, m1[n], 0, 0, 0);
                    }
                }
            #pragma unroll
            for (int n = 0; n < 2; ++n)
                #pragma unroll
                for (int i = 0; i < 4; ++i) {
                    int row = ((lane>>4)<<2) + i;
                    int col = nh*128 + w*32 + n*16 + l15;
                    out[(size_t)(sblk*16 + row)*LE + (size_t)step*E + col]
                        = m1[n][i] + b3v[nh][n];
                }
            __syncthreads();
        }
    };

    // X(0) prefetch
    {
        const char* xsrc = (const char*)g_Xs
            + (size_t)((mt>>1)*4)*8192 + ((mt&1)*32)*128;
        #pragma unroll
        for (int it = 0; it < 4; ++it) {
            int s = tid + it*256;
            int kt = s >> 8, rb = s & 255;
            __builtin_amdgcn_global_load_lds((gu32*)(xsrc + (size_t)kt*8192 + rb*16),
                                             (lu32*)(Alds + s*16), 16, 0, 0);
        }
    }

    #pragma unroll 1
    for (int step = 0; step < 127; ++step) {
        const int cur = step & 1, nxt = cur ^ 1;
        if (duty && step >= 1) do_mlp(step);
        __syncthreads();
        // stage H(step) -> A tiles 4..11 (32 KB)
        {
            const char* hsrc = (const char*)&g_Hs[cur][0]
                + (size_t)((mt>>1)*8)*8192 + ((mt&1)*32)*128;
            char* hdst = Alds + 16384;
            #pragma unroll
            for (int it = 0; it < 8; ++it) {
                int s = tid + it*256;
                int kt = s >> 8, rb = s & 255;
                __builtin_amdgcn_global_load_lds((gu32*)(hsrc + (size_t)kt*8192 + rb*16),
                                                 (lu32*)(hdst + s*16), 16, 0, 0);
            }
        }
        asm volatile("s_waitcnt vmcnt(0)\n\ts_barrier" ::: "memory");
        // MFMA: 24 k-slices, B from registers
        f32x4 acc[2][4];
        #pragma unroll
        for (int m = 0; m < 2; ++m)
            #pragma unroll
            for (int n = 0; n < 4; ++n) acc[m][n] = (f32x4){0,0,0,0};
        #pragma unroll
        for (int kt = 0; kt < 12; ++kt)
            #pragma unroll
            for (int kkl = 0; kkl < 2; ++kkl) {
                int kb = kkl*64 + klo;
                f16x8 a0 = *(const f16x8*)(Alds + kt*4096 + l15*128 + (kb ^ xr));
                f16x8 a1 = *(const f16x8*)(Alds + kt*4096 + (16+l15)*128 + (kb ^ xr));
                #pragma unroll
                for (int n = 0; n < 4; ++n) {
                    acc[0][n] = __builtin_amdgcn_mfma_f32_16x16x32_f16(
                        a0, bw[kt*2+kkl][n], acc[0][n], 0, 0, 0);
                    acc[1][n] = __builtin_amdgcn_mfma_f32_16x16x32_f16(
                        a1, bw[kt*2+kkl][n], acc[1][n], 0, 0, 0);
                }
            }
        // epilogue: acc -> Glds
        #pragma unroll
        for (int m = 0; m < 2; ++m)
            #pragma unroll
            for (int n = 0; n < 4; ++n)
                #pragma unroll
                for (int i = 0; i < 4; ++i) {
                    int row = m*16 + ((lane>>4)<<2) + i;
                    int col = w*64 + n*16 + l15;
                    Glds[row][col] = acc[m][n][i];
                }
        __syncthreads();
        // X(step+1) prefetch (A X-region free: all waves past kk-loop)
        if (step < 126) {
            const char* xsrc = (const char*)g_Xs
                + (size_t)(((step+1)*16 + (mt>>1))*4)*8192 + ((mt&1)*32)*128;
            #pragma unroll
            for (int it = 0; it < 4; ++it) {
                int s = tid + it*256;
                int kt = s >> 8, rb = s & 255;
                __builtin_amdgcn_global_load_lds((gu32*)(xsrc + (size_t)kt*8192 + rb*16),
                                                 (lu32*)(Alds + s*16), 16, 0, 0);
            }
        }
        // cell update: 8 cells/thread, c in registers
        {
            char* hdstg = (char*)&g_Hs[nxt][0]
                + (size_t)((mt>>1)*8 + nt)*8192 + ((mt&1)*32)*128;
            #pragma unroll
            for (int i2 = 0; i2 < 8; ++i2) {
                int bl = blb + i2;
                float4 gv = *(const float4*)&Glds[bl][jl*4];
                float iv = sigm(gv.x + bsv.x);
                float fv = sigm(gv.y + bsv.y);
                float gg = tanhf(gv.z + bsv.z);
                float ov = sigm(gv.w + bsv.w);
                float cv = fv * creg[i2] + iv * gg;
                creg[i2] = cv;
                float hv = ov * tanhf(cv);
                *(f16*)(hdstg + bl*128 + ((jl*2) ^ ((bl & 7) << 4))) = (f16)hv;
            }
        }
        grid_barrier((unsigned)(step + 1));
    }
    if (duty) do_mlp(127);
}

// ---------------------------------------------------------------------------
extern "C" void kernel_launch(void* const* d_in, const int* in_sizes, int n_in,
                              void* d_out, int out_size, void* d_ws, size_t ws_size,
                              hipStream_t stream) {
    (void)in_sizes; (void)n_in; (void)out_size; (void)d_ws; (void)ws_size;
    const float* hidden = (const float*)d_in[0];
    const float* padded = (const float*)d_in[1];
    const float* W_ih   = (const float*)d_in[2];
    const float* W_hh   = (const float*)d_in[3];
    const float* b_ih   = (const float*)d_in[4];
    const float* b_hh   = (const float*)d_in[5];
    const float* W1     = (const float*)d_in[6];
    const float* b1     = (const float*)d_in[7];
    const float* W2     = (const float*)d_in[8];
    const float* b2     = (const float*)d_in[9];
    const float* W3     = (const float*)d_in[10];
    const float* b3     = (const float*)d_in[11];
    float* out = (float*)d_out;

    conv_w<<<768, 256, 0, stream>>>(W_ih, W_hh, b_ih, b_hh);
    conv_mlp<<<56, 256, 0, stream>>>(W1, W2, W3);
    conv_x<<<16256, 256, 0, stream>>>(padded);
    init_kernel<<<2048, 256, 0, stream>>>(hidden, out);
    step_all<<<256, 256, 0, stream>>>(b1, b2, b3, out);
}

// Round 7
// 3764.790 us; speedup vs baseline: 1.6707x; 1.6707x over previous
//
#include <hip/hip_runtime.h>
#include <math.h>
#include <stdint.h>

#define B 1024
#define H 512
#define E 256
#define L 128
#define LE (L*E)   // 32768

typedef _Float16 f16;
typedef _Float16 f16x8 __attribute__((ext_vector_type(8)));
typedef float f32x4 __attribute__((ext_vector_type(4)));
typedef const __attribute__((address_space(1))) uint32_t gu32;
typedef __attribute__((address_space(3))) uint32_t lu32;

// ---------------------------------------------------------------------------
// Persistent state in module device globals. Everything rewritten every call.
// ---------------------------------------------------------------------------
__device__ __align__(16) f16 g_Xs[127*16*4*4096];   // X images [t][mt16][kt:4] 64x64
__device__ __align__(16) f16 g_Hh[128*16*8*4096];   // h(t) images, t=0..127 (134 MB)
__device__ __align__(16) f16 g_Ws[16*12*8192];      // gates W' [itile:16][kt:12] 128x64
__device__ __align__(16) f16 g_W1s[8*8192];         // W1' [kt:8] 128x64
__device__ __align__(16) f16 g_W2s[2*8192];         // W2' [kt:2] 128x64
__device__ __align__(16) f16 g_W3s[4*8192];         // W3' [nh:2][kt:2] 128x64
__device__ __align__(16) float g_bsum[2048];        // b_ih+b_hh, n=j*4+g order
__device__ unsigned int g_bar_count;
__device__ unsigned int g_bar_phase;

__device__ __forceinline__ float sigm(float x) { return 1.0f / (1.0f + expf(-x)); }

#define NBLK 256u

// Software grid barrier (worked in round 6: validated twice incl. replays).
__device__ __forceinline__ void grid_barrier(unsigned int target) {
    __syncthreads();   // compiler drains vmcnt before s_barrier -> stores in L2
    if (threadIdx.x == 0) {
        unsigned int prev = __hip_atomic_fetch_add(&g_bar_count, 1u,
                              __ATOMIC_ACQ_REL, __HIP_MEMORY_SCOPE_AGENT);
        if (prev == NBLK - 1u) {
            __hip_atomic_store(&g_bar_count, 0u, __ATOMIC_RELAXED, __HIP_MEMORY_SCOPE_AGENT);
            __hip_atomic_store(&g_bar_phase, target, __ATOMIC_RELEASE, __HIP_MEMORY_SCOPE_AGENT);
        } else {
            while (__hip_atomic_load(&g_bar_phase, __ATOMIC_ACQUIRE,
                                     __HIP_MEMORY_SCOPE_AGENT) < target)
                __builtin_amdgcn_s_sleep(1);
        }
    }
    __syncthreads();
}

// ---------------------------------------------------------------------------
// conv_w: gates W' fp16 tile images (gate-interleaved n=j*4+g) + bias sums
// ---------------------------------------------------------------------------
__global__ __launch_bounds__(256) void conv_w(
    const float* __restrict__ W_ih, const float* __restrict__ W_hh,
    const float* __restrict__ b_ih, const float* __restrict__ b_hh)
{
    int gid = blockIdx.x*256 + threadIdx.x;   // 196608
    int kb  = gid & 7;
    int r1  = gid >> 3;
    int row = r1 & 127;
    int r2  = r1 >> 7;
    int kt  = r2 % 12;
    int nt  = r2 / 12;
    int n = nt*128 + row;
    int g = n & 3, j = n >> 2;
    int wrow = g*512 + j;
    int k = kt*64 + kb*8;
    const float* src = (k < 256) ? (W_ih + wrow*256 + k)
                                 : (W_hh + wrow*512 + (k - 256));
    f16x8 v;
    #pragma unroll
    for (int e = 0; e < 8; ++e) v[e] = (f16)src[e];
    char* dst = (char*)g_Ws + (size_t)(nt*12 + kt)*16384
              + row*128 + ((kb*16) ^ ((row & 7) << 4));
    *(f16x8*)dst = v;
    if (gid < 2048) {
        int gg = gid & 3, jj = gid >> 2;
        g_bsum[gid] = b_ih[gg*512 + jj] + b_hh[gg*512 + jj];
    }
}

// ---------------------------------------------------------------------------
// conv_mlp: W1/W2/W3 fp16 tile images
// ---------------------------------------------------------------------------
__global__ __launch_bounds__(256) void conv_mlp(
    const float* __restrict__ W1, const float* __restrict__ W2,
    const float* __restrict__ W3)
{
    int gid = blockIdx.x*256 + threadIdx.x;   // 14336
    if (gid < 8192) {                         // W1 (128,512) -> 8 tiles
        int s = gid;
        int kb = s & 7, row = (s >> 3) & 127, kt = s >> 10;
        const float* src = W1 + row*512 + kt*64 + kb*8;
        f16x8 v;
        #pragma unroll
        for (int e = 0; e < 8; ++e) v[e] = (f16)src[e];
        char* dst = (char*)g_W1s + (size_t)kt*16384
                  + row*128 + ((kb*16) ^ ((row & 7) << 4));
        *(f16x8*)dst = v;
    } else if (gid < 10240) {                 // W2 (128,128) -> 2 tiles
        int s = gid - 8192;
        int kb = s & 7, row = (s >> 3) & 127, kt = s >> 10;
        const float* src = W2 + row*128 + kt*64 + kb*8;
        f16x8 v;
        #pragma unroll
        for (int e = 0; e < 8; ++e) v[e] = (f16)src[e];
        char* dst = (char*)g_W2s + (size_t)kt*16384
                  + row*128 + ((kb*16) ^ ((row & 7) << 4));
        *(f16x8*)dst = v;
    } else if (gid < 14336) {                 // W3 (256,128) -> [nh:2][kt:2]
        int s = gid - 10240;
        int kb = s & 7, r256 = (s >> 3) & 255, kt = s >> 11;
        int nh = r256 >> 7, row = r256 & 127;
        const float* src = W3 + r256*128 + kt*64 + kb*8;
        f16x8 v;
        #pragma unroll
        for (int e = 0; e < 8; ++e) v[e] = (f16)src[e];
        char* dst = (char*)g_W3s + (size_t)(nh*2 + kt)*16384
                  + row*128 + ((kb*16) ^ ((row & 7) << 4));
        *(f16x8*)dst = v;
    }
}

// ---------------------------------------------------------------------------
// conv_x: X fp16 tile images (coalesced: 32 consecutive lanes = 1 KB)
// ---------------------------------------------------------------------------
__global__ __launch_bounds__(256) void conv_x(const float* __restrict__ padded)
{
    int gid = blockIdx.x*256 + threadIdx.x;   // 127*1024*32 = 4161536 exact
    int kq = gid & 31;
    int b  = (gid >> 5) & 1023;
    int t  = gid >> 15;
    const float* src = padded + (size_t)b*LE + t*E + kq*8;
    float4 v0 = *(const float4*)src;
    float4 v1 = *(const float4*)(src + 4);
    f16x8 v;
    v[0]=(f16)v0.x; v[1]=(f16)v0.y; v[2]=(f16)v0.z; v[3]=(f16)v0.w;
    v[4]=(f16)v1.x; v[5]=(f16)v1.y; v[6]=(f16)v1.z; v[7]=(f16)v1.w;
    int kt = kq >> 3, kb = kq & 7;
    int row = b & 63, mt16 = b >> 6;
    char* dst = (char*)g_Xs + (size_t)((t*16 + mt16)*4 + kt)*8192
              + row*128 + ((kb*16) ^ ((row & 7) << 4));
    *(f16x8*)dst = v;
}

// ---------------------------------------------------------------------------
// init: g_Hh[0] <- hidden image, out row 0 <- one-hot, barrier reset
// ---------------------------------------------------------------------------
__global__ __launch_bounds__(256) void init_kernel(
    const float* __restrict__ hidden, float* __restrict__ out)
{
    int i = blockIdx.x * 256 + threadIdx.x;
    if (i == 0) { g_bar_count = 0u; g_bar_phase = 0u; }
    if (i < B*H) {
        float hv = hidden[i];
        int b = i >> 9, j = i & 511;
        int mt = b >> 6, row = b & 63, kt = j >> 6, kk = j & 63;
        char* dst = (char*)g_Hh + (size_t)(mt*8 + kt)*8192
                  + row*128 + ((kk*2) ^ ((row & 7) << 4));
        *(f16*)dst = (f16)hv;
    }
    if (i < B*E) {
        int b = i >> 8, e = i & 255;
        out[b*LE + e] = (e == 0) ? 1.0f : 0.0f;
    }
}

// ---------------------------------------------------------------------------
// step_all: persistent gates-only recurrence. 256 blocks x 256 thr (4 waves),
// 1 block/CU. Block (mt8,nt) = rows [mt8*128,+128) x gate-cols [nt*64,+64).
// B (96 KB) persistent in LDS, loaded ONCE. Per step: depth-2 counted-vmcnt
// A staging (X||H images, 12 kt x 16 KB) -> 192 MFMA/wave -> shfl-transpose
// epilogue (4 gates -> 1 lane), c in regs, h -> g_Hh[t+1] image -> barrier.
// ---------------------------------------------------------------------------
__global__ __launch_bounds__(256, 1) void step_all()
{
    __shared__ __align__(16) char lds[131072];
    char* Bb = lds;             // 12 x 8192 persistent B images
    char* Ab = lds + 98304;     // 2 x 16384 A dbuf

    const int tid  = threadIdx.x;
    const int lane = tid & 63;
    const int wv   = tid >> 6;          // 0..3 (M quarter)
    const int mt8  = blockIdx.x >> 5;   // 0..7
    const int nt   = blockIdx.x & 31;   // 0..31
    const int l15  = lane & 15;
    const int p    = l15 & 3;           // gate id within 4-lane group
    const int klo  = (lane >> 4) << 4;

    // ---- persistent B load (once): rows (nt&1)*64..+64 of itile nt>>1 ----
    {
        const char* src = (const char*)g_Ws + (size_t)(nt >> 1)*12*16384
                        + (size_t)(nt & 1)*64*128;
        #pragma unroll
        for (int it = 0; it < 24; ++it) {
            int c = wv*24 + it;             // 0..95 chunks of 1KB
            int kt = c >> 3, cc = c & 7;
            __builtin_amdgcn_global_load_lds(
                (gu32*)(src + (size_t)kt*16384 + cc*1024 + lane*16),
                (lu32*)(Bb + c*1024 + lane*16), 16, 0, 0);
        }
    }
    float4 bs4[4];
    #pragma unroll
    for (int n = 0; n < 4; ++n)
        bs4[n] = *(const float4*)&g_bsum[nt*64 + n*16 + (l15 >> 2)*4];

    float creg[2][4];
    #pragma unroll
    for (int m = 0; m < 2; ++m)
        #pragma unroll
        for (int n = 0; n < 4; ++n) creg[m][n] = 0.0f;

    asm volatile("s_waitcnt vmcnt(0)" ::: "memory");
    __syncthreads();

    auto stageA = [&](int t, int kt, int buf) {
        char* dst = Ab + buf*16384;
        #pragma unroll
        for (int it = 0; it < 4; ++it) {
            int c = wv*4 + it;              // 0..15 chunks of 1KB (16 KB)
            int sub = c >> 3, cc = c & 7;   // sub: which 64-row image
            const char* src = (kt < 4)
                ? (const char*)g_Xs + (size_t)((t*16 + mt8*2 + sub)*4 + kt)*8192
                : (const char*)g_Hh + (size_t)((t*16 + mt8*2 + sub)*8 + (kt-4))*8192;
            __builtin_amdgcn_global_load_lds(
                (gu32*)(src + cc*1024 + lane*16),
                (lu32*)(dst + c*1024 + lane*16), 16, 0, 0);
        }
    };

    #pragma unroll 1
    for (int t = 0; t < 127; ++t) {
        stageA(t, 0, 0);
        stageA(t, 1, 1);
        f32x4 acc[2][4];
        #pragma unroll
        for (int m = 0; m < 2; ++m)
            #pragma unroll
            for (int n = 0; n < 4; ++n) acc[m][n] = (f32x4){0.f,0.f,0.f,0.f};

        #pragma unroll
        for (int kt = 0; kt < 12; ++kt) {
            if (kt < 11) asm volatile("s_waitcnt vmcnt(4)\n\ts_barrier" ::: "memory");
            else         asm volatile("s_waitcnt vmcnt(0)\n\ts_barrier" ::: "memory");
            const char* Ar = Ab + (kt & 1)*16384;
            const char* Br = Bb + kt*8192;
            #pragma unroll
            for (int kkl = 0; kkl < 2; ++kkl) {
                const int kb = kkl*64 + klo;
                f16x8 a[2], b[4];
                #pragma unroll
                for (int m = 0; m < 2; ++m) {
                    int r = wv*32 + m*16 + l15;
                    a[m] = *(const f16x8*)(Ar + (r >> 6)*8192 + (r & 63)*128
                                           + (kb ^ ((r & 7) << 4)));
                }
                #pragma unroll
                for (int n = 0; n < 4; ++n) {
                    int r = n*16 + l15;
                    b[n] = *(const f16x8*)(Br + r*128 + (kb ^ ((r & 7) << 4)));
                }
                #pragma unroll
                for (int m = 0; m < 2; ++m)
                    #pragma unroll
                    for (int n = 0; n < 4; ++n)
                        acc[m][n] = __builtin_amdgcn_mfma_f32_16x16x32_f16(
                            a[m], b[n], acc[m][n], 0, 0, 0);
            }
            asm volatile("s_barrier" ::: "memory");   // reads done before restage
            if (kt < 10) stageA(t, kt + 2, kt & 1);
        }

        // epilogue: 4x4 shfl transpose within lane groups -> lane owns 1 cell
        // per frag (all 4 gates); c in regs; h -> g_Hh[t+1] image.
        char* hout = (char*)g_Hh + (size_t)(t + 1)*16*8*8192;
        #pragma unroll
        for (int m = 0; m < 2; ++m)
            #pragma unroll
            for (int n = 0; n < 4; ++n) {
                float v0 = acc[m][n][0], v1 = acc[m][n][1];
                float v2 = acc[m][n][2], v3 = acc[m][n][3];
                float s, r;
                s = (p & 1) ? v0 : v1; r = __shfl_xor(s, 1); if (p & 1) v0 = r; else v1 = r;
                s = (p & 1) ? v2 : v3; r = __shfl_xor(s, 1); if (p & 1) v2 = r; else v3 = r;
                s = (p & 2) ? v0 : v2; r = __shfl_xor(s, 2); if (p & 2) v0 = r; else v2 = r;
                s = (p & 2) ? v1 : v3; r = __shfl_xor(s, 2); if (p & 2) v1 = r; else v3 = r;
                // now v0..v3 = gates i,f,g,o of row (lane>>4)*4+p, j = n*4+(l15>>2)
                float iv = sigm(v0 + bs4[n].x);
                float fv = sigm(v1 + bs4[n].y);
                float gg = tanhf(v2 + bs4[n].z);
                float ov = sigm(v3 + bs4[n].w);
                float cv = fv * creg[m][n] + iv * gg;
                creg[m][n] = cv;
                float hv = ov * tanhf(cv);
                int row = mt8*128 + wv*32 + m*16 + ((lane >> 4) << 2) + p;
                int jg  = nt*16 + n*4 + (l15 >> 2);
                char* hd = hout + (size_t)((row >> 6)*8 + (jg >> 6))*8192
                         + (row & 63)*128 + (((jg & 63)*2) ^ (((row & 63) & 7) << 4));
                *(f16*)hd = (f16)hv;
            }
        grid_barrier((unsigned)(t + 1));
    }
}

// ---------------------------------------------------------------------------
// mlp_all: batched 3-layer MLP for ALL tokens (round-4 proven structure).
// Block bi: tok = 1 + bi/16 (reads g_Hh[tok]), rows [mt*64,+64), mt = bi&15.
// ---------------------------------------------------------------------------
__global__ __launch_bounds__(256) void mlp_all(
    const float* __restrict__ b1, const float* __restrict__ b2,
    const float* __restrict__ b3, float* __restrict__ out)
{
    __shared__ char lds[65536];
    char* Wb = lds;            // 2 x 16384
    char* Ab = lds + 32768;    // 2 x 8192 (later Z2)
    char* Z1 = lds + 49152;    // 16384
    const int tid  = threadIdx.x;
    const int lane = tid & 63;
    const int w    = tid >> 6;
    const int bi   = blockIdx.x;
    const int tok  = 1 + (bi >> 4);
    const int mt   = bi & 15;
    const char* gH = (const char*)g_Hh + (size_t)(tok*16 + mt)*8*8192;
    float* outb = out + (size_t)(mt*64)*LE + (size_t)tok*E;

    float b1v[2], b2v[2], b3v[2][2];
    #pragma unroll
    for (int n = 0; n < 2; ++n) {
        int col = w*32 + n*16 + (lane & 15);
        b1v[n] = b1[col]; b2v[n] = b2[col];
        b3v[0][n] = b3[col]; b3v[1][n] = b3[128 + col];
    }
    const int kb0_0 = ((lane >> 4) << 4);

    f32x4 acc[4][2];
    #pragma unroll
    for (int m = 0; m < 4; ++m) { acc[m][0] = (f32x4){0,0,0,0}; acc[m][1] = (f32x4){0,0,0,0}; }

    #pragma unroll
    for (int it = 0; it < 2; ++it) {
        int c = w*2 + it;
        __builtin_amdgcn_global_load_lds((gu32*)(gH + c*1024 + lane*16),
                                         (lu32*)(Ab + c*1024 + lane*16), 16, 0, 0);
    }
    #pragma unroll
    for (int it = 0; it < 4; ++it) {
        int c = w*4 + it;
        __builtin_amdgcn_global_load_lds((gu32*)((const char*)g_W1s + c*1024 + lane*16),
                                         (lu32*)(Wb + c*1024 + lane*16), 16, 0, 0);
    }
    __syncthreads();

    for (int kt = 0; kt < 8; ++kt) {
        const int cur = kt & 1;
        if (kt < 7) {
            const char* gA = gH + (size_t)(kt+1)*8192;
            const char* gW = (const char*)g_W1s + (size_t)(kt+1)*16384;
            char* dA = Ab + (cur^1)*8192;
            char* dW = Wb + (cur^1)*16384;
            #pragma unroll
            for (int it = 0; it < 2; ++it) {
                int c = w*2 + it;
                __builtin_amdgcn_global_load_lds((gu32*)(gA + c*1024 + lane*16),
                                                 (lu32*)(dA + c*1024 + lane*16), 16, 0, 0);
            }
            #pragma unroll
            for (int it = 0; it < 4; ++it) {
                int c = w*4 + it;
                __builtin_amdgcn_global_load_lds((gu32*)(gW + c*1024 + lane*16),
                                                 (lu32*)(dW + c*1024 + lane*16), 16, 0, 0);
            }
        }
        const char* Ar = Ab + cur*8192;
        const char* Br = Wb + cur*16384;
        #pragma unroll
        for (int kk = 0; kk < 2; ++kk) {
            const int kb0 = kk*64 + kb0_0;
            f16x8 a[4], b[2];
            #pragma unroll
            for (int m = 0; m < 4; ++m) {
                int ar = m*16 + (lane & 15);
                a[m] = *(const f16x8*)(Ar + ar*128 + (kb0 ^ ((ar & 7) << 4)));
            }
            #pragma unroll
            for (int n = 0; n < 2; ++n) {
                int br = w*32 + n*16 + (lane & 15);
                b[n] = *(const f16x8*)(Br + br*128 + (kb0 ^ ((br & 7) << 4)));
            }
            #pragma unroll
            for (int m = 0; m < 4; ++m)
                #pragma unroll
                for (int n = 0; n < 2; ++n)
                    acc[m][n] = __builtin_amdgcn_mfma_f32_16x16x32_f16(a[m], b[n], acc[m][n], 0, 0, 0);
        }
        __syncthreads();
    }

    #pragma unroll
    for (int m = 0; m < 4; ++m)
        #pragma unroll
        for (int n = 0; n < 2; ++n)
            #pragma unroll
            for (int i = 0; i < 4; ++i) {
                int row = m*16 + ((lane >> 4) << 2) + i;
                int col = w*32 + n*16 + (lane & 15);
                float v = fmaxf(acc[m][n][i] + b1v[n], 0.0f);
                *(f16*)(Z1 + (col >> 6)*8192 + row*128
                        + (((col & 63)*2) ^ ((row & 7) << 4))) = (f16)v;
            }
    __syncthreads();

    #pragma unroll
    for (int it = 0; it < 8; ++it) {
        int c = w*8 + it;
        __builtin_amdgcn_global_load_lds((gu32*)((const char*)g_W2s + c*1024 + lane*16),
                                         (lu32*)(Wb + c*1024 + lane*16), 16, 0, 0);
    }
    __syncthreads();
    #pragma unroll
    for (int m = 0; m < 4; ++m) { acc[m][0] = (f32x4){0,0,0,0}; acc[m][1] = (f32x4){0,0,0,0}; }
    #pragma unroll
    for (int kt = 0; kt < 2; ++kt)
        #pragma unroll
        for (int kk = 0; kk < 2; ++kk) {
            const int kb0 = kk*64 + kb0_0;
            f16x8 a[4], b[2];
            #pragma unroll
            for (int m = 0; m < 4; ++m) {
                int ar = m*16 + (lane & 15);
                a[m] = *(const f16x8*)(Z1 + kt*8192 + ar*128 + (kb0 ^ ((ar & 7) << 4)));
            }
            #pragma unroll
            for (int n = 0; n < 2; ++n) {
                int br = w*32 + n*16 + (lane & 15);
                b[n] = *(const f16x8*)(Wb + kt*16384 + br*128 + (kb0 ^ ((br & 7) << 4)));
            }
            #pragma unroll
            for (int m = 0; m < 4; ++m)
                #pragma unroll
                for (int n = 0; n < 2; ++n)
                    acc[m][n] = __builtin_amdgcn_mfma_f32_16x16x32_f16(a[m], b[n], acc[m][n], 0, 0, 0);
        }
    __syncthreads();

    #pragma unroll
    for (int m = 0; m < 4; ++m)
        #pragma unroll
        for (int n = 0; n < 2; ++n)
            #pragma unroll
            for (int i = 0; i < 4; ++i) {
                int row = m*16 + ((lane >> 4) << 2) + i;
                int col = w*32 + n*16 + (lane & 15);
                float v = fmaxf(acc[m][n][i] + b2v[n], 0.0f);
                *(f16*)(Ab + (col >> 6)*8192 + row*128
                        + (((col & 63)*2) ^ ((row & 7) << 4))) = (f16)v;
            }
    __syncthreads();

    #pragma unroll
    for (int nh = 0; nh < 2; ++nh) {
        #pragma unroll
        for (int it = 0; it < 8; ++it) {
            int c = w*8 + it;
            __builtin_amdgcn_global_load_lds(
                (gu32*)((const char*)g_W3s + (size_t)nh*32768 + c*1024 + lane*16),
                (lu32*)(Wb + c*1024 + lane*16), 16, 0, 0);
        }
        __syncthreads();
        #pragma unroll
        for (int m = 0; m < 4; ++m) { acc[m][0] = (f32x4){0,0,0,0}; acc[m][1] = (f32x4){0,0,0,0}; }
        #pragma unroll
        for (int kt = 0; kt < 2; ++kt)
            #pragma unroll
            for (int kk = 0; kk < 2; ++kk) {
                const int kb0 = kk*64 + kb0_0;
                f16x8 a[4], b[2];
                #pragma unroll
                for (int m = 0; m < 4; ++m) {
                    int ar = m*16 + (lane & 15);
                    a[m] = *(const f16x8*)(Ab + kt*8192 + ar*128 + (kb0 ^ ((ar & 7) << 4)));
                }
                #pragma unroll
                for (int n = 0; n < 2; ++n) {
                    int br = w*32 + n*16 + (lane & 15);
                    b[n] = *(const f16x8*)(Wb + kt*16384 + br*128 + (kb0 ^ ((br & 7) << 4)));
                }
                #pragma unroll
                for (int m = 0; m < 4; ++m)
                    #pragma unroll
                    for (int n = 0; n < 2; ++n)
                        acc[m][n] = __builtin_amdgcn_mfma_f32_16x16x32_f16(a[m], b[n], acc[m][n], 0, 0, 0);
            }
        #pragma unroll
        for (int m = 0; m < 4; ++m)
            #pragma unroll
            for (int n = 0; n < 2; ++n)
                #pragma unroll
                for (int i = 0; i < 4; ++i) {
                    int row = m*16 + ((lane >> 4) << 2) + i;
                    int col = nh*128 + w*32 + n*16 + (lane & 15);
                    outb[(size_t)row*LE + col] = acc[m][n][i] + b3v[nh][n];
                }
        __syncthreads();
    }
}

// ---------------------------------------------------------------------------
extern "C" void kernel_launch(void* const* d_in, const int* in_sizes, int n_in,
                              void* d_out, int out_size, void* d_ws, size_t ws_size,
                              hipStream_t stream) {
    (void)in_sizes; (void)n_in; (void)out_size; (void)d_ws; (void)ws_size;
    const float* hidden = (const float*)d_in[0];
    const float* padded = (const float*)d_in[1];
    const float* W_ih   = (const float*)d_in[2];
    const float* W_hh   = (const float*)d_in[3];
    const float* b_ih   = (const float*)d_in[4];
    const float* b_hh   = (const float*)d_in[5];
    const float* W1     = (const float*)d_in[6];
    const float* b1     = (const float*)d_in[7];
    const float* W2     = (const float*)d_in[8];
    const float* b2     = (const float*)d_in[9];
    const float* W3     = (const float*)d_in[10];
    const float* b3     = (const float*)d_in[11];
    float* out = (float*)d_out;

    conv_w<<<768, 256, 0, stream>>>(W_ih, W_hh, b_ih, b_hh);
    conv_mlp<<<56, 256, 0, stream>>>(W1, W2, W3);
    conv_x<<<16256, 256, 0, stream>>>(padded);
    init_kernel<<<2048, 256, 0, stream>>>(hidden, out);
    step_all<<<256, 256, 0, stream>>>();
    mlp_all<<<2032, 256, 0, stream>>>(b1, b2, b3, out);
}

// Round 8
// 1872.691 us; speedup vs baseline: 3.3586x; 2.0104x over previous
//
#include <hip/hip_runtime.h>
#include <math.h>
#include <stdint.h>

#define B 1024
#define H 512
#define E 256
#define L 128
#define LE (L*E)   // 32768

typedef _Float16 f16;
typedef _Float16 f16x8 __attribute__((ext_vector_type(8)));
typedef float f32x4 __attribute__((ext_vector_type(4)));
typedef const __attribute__((address_space(1))) uint32_t gu32;
typedef __attribute__((address_space(3))) uint32_t lu32;

// ---------------------------------------------------------------------------
// Persistent state in module device globals. Everything rewritten every call.
// ---------------------------------------------------------------------------
__device__ __align__(16) f16 g_Xs[127*16*4*4096];   // X images [t][mt16][kt:4] 64x64
__device__ __align__(16) f16 g_Hh[128*16*8*4096];   // h(t) images, t=0..127 (134 MB)
__device__ __align__(16) f16 g_Ws[16*12*8192];      // gates W' [itile:16][kt:12] 128x64
__device__ __align__(16) f16 g_W1s[8*8192];         // W1' [kt:8] 128x64
__device__ __align__(16) f16 g_W2s[2*8192];         // W2' [kt:2] 128x64
__device__ __align__(16) f16 g_W3s[4*8192];         // W3' [nh:2][kt:2] 128x64
__device__ __align__(16) float g_bsum[2048];        // b_ih+b_hh, n=j*4+g order

// Per-group barrier state: 8 independent 32-block groups, one cacheline each.
struct __align__(128) Bar { unsigned int cnt; unsigned int phase; unsigned int pad[30]; };
__device__ Bar g_bars[8];

__device__ __forceinline__ float sigm(float x) { return 1.0f / (1.0f + expf(-x)); }

// Group barrier: arrival = ACQ_REL fetch_add (release flushes this block's h
// stores to the device coherence point). Spin = RELAXED atomic loads (go to
// the coherence point, NO per-poll cache invalidate -- round-7's storm).
// Exit = ONE acquire load (single invalidate so fresh H is visible).
__device__ __forceinline__ void group_barrier(int g, unsigned int target) {
    __syncthreads();
    if (threadIdx.x == 0) {
        unsigned int prev = __hip_atomic_fetch_add(&g_bars[g].cnt, 1u,
                              __ATOMIC_ACQ_REL, __HIP_MEMORY_SCOPE_AGENT);
        if (prev == 31u) {
            __hip_atomic_store(&g_bars[g].cnt, 0u, __ATOMIC_RELAXED, __HIP_MEMORY_SCOPE_AGENT);
            __hip_atomic_store(&g_bars[g].phase, target, __ATOMIC_RELEASE, __HIP_MEMORY_SCOPE_AGENT);
        } else {
            while (__hip_atomic_load(&g_bars[g].phase, __ATOMIC_RELAXED,
                                     __HIP_MEMORY_SCOPE_AGENT) < target)
                __builtin_amdgcn_s_sleep(4);
            (void)__hip_atomic_load(&g_bars[g].phase, __ATOMIC_ACQUIRE,
                                    __HIP_MEMORY_SCOPE_AGENT);
        }
    }
    __syncthreads();
}

// ---------------------------------------------------------------------------
// conv_w: gates W' fp16 tile images (gate-interleaved n=j*4+g) + bias sums
// ---------------------------------------------------------------------------
__global__ __launch_bounds__(256) void conv_w(
    const float* __restrict__ W_ih, const float* __restrict__ W_hh,
    const float* __restrict__ b_ih, const float* __restrict__ b_hh)
{
    int gid = blockIdx.x*256 + threadIdx.x;   // 196608
    int kb  = gid & 7;
    int r1  = gid >> 3;
    int row = r1 & 127;
    int r2  = r1 >> 7;
    int kt  = r2 % 12;
    int nt  = r2 / 12;
    int n = nt*128 + row;
    int g = n & 3, j = n >> 2;
    int wrow = g*512 + j;
    int k = kt*64 + kb*8;
    const float* src = (k < 256) ? (W_ih + wrow*256 + k)
                                 : (W_hh + wrow*512 + (k - 256));
    f16x8 v;
    #pragma unroll
    for (int e = 0; e < 8; ++e) v[e] = (f16)src[e];
    char* dst = (char*)g_Ws + (size_t)(nt*12 + kt)*16384
              + row*128 + ((kb*16) ^ ((row & 7) << 4));
    *(f16x8*)dst = v;
    if (gid < 2048) {
        int gg = gid & 3, jj = gid >> 2;
        g_bsum[gid] = b_ih[gg*512 + jj] + b_hh[gg*512 + jj];
    }
}

// ---------------------------------------------------------------------------
// conv_mlp: W1/W2/W3 fp16 tile images
// ---------------------------------------------------------------------------
__global__ __launch_bounds__(256) void conv_mlp(
    const float* __restrict__ W1, const float* __restrict__ W2,
    const float* __restrict__ W3)
{
    int gid = blockIdx.x*256 + threadIdx.x;   // 14336
    if (gid < 8192) {                         // W1 (128,512) -> 8 tiles
        int s = gid;
        int kb = s & 7, row = (s >> 3) & 127, kt = s >> 10;
        const float* src = W1 + row*512 + kt*64 + kb*8;
        f16x8 v;
        #pragma unroll
        for (int e = 0; e < 8; ++e) v[e] = (f16)src[e];
        char* dst = (char*)g_W1s + (size_t)kt*16384
                  + row*128 + ((kb*16) ^ ((row & 7) << 4));
        *(f16x8*)dst = v;
    } else if (gid < 10240) {                 // W2 (128,128) -> 2 tiles
        int s = gid - 8192;
        int kb = s & 7, row = (s >> 3) & 127, kt = s >> 10;
        const float* src = W2 + row*128 + kt*64 + kb*8;
        f16x8 v;
        #pragma unroll
        for (int e = 0; e < 8; ++e) v[e] = (f16)src[e];
        char* dst = (char*)g_W2s + (size_t)kt*16384
                  + row*128 + ((kb*16) ^ ((row & 7) << 4));
        *(f16x8*)dst = v;
    } else if (gid < 14336) {                 // W3 (256,128) -> [nh:2][kt:2]
        int s = gid - 10240;
        int kb = s & 7, r256 = (s >> 3) & 255, kt = s >> 11;
        int nh = r256 >> 7, row = r256 & 127;
        const float* src = W3 + r256*128 + kt*64 + kb*8;
        f16x8 v;
        #pragma unroll
        for (int e = 0; e < 8; ++e) v[e] = (f16)src[e];
        char* dst = (char*)g_W3s + (size_t)(nh*2 + kt)*16384
                  + row*128 + ((kb*16) ^ ((row & 7) << 4));
        *(f16x8*)dst = v;
    }
}

// ---------------------------------------------------------------------------
// conv_x: X fp16 tile images (coalesced: 32 consecutive lanes = 1 KB)
// ---------------------------------------------------------------------------
__global__ __launch_bounds__(256) void conv_x(const float* __restrict__ padded)
{
    int gid = blockIdx.x*256 + threadIdx.x;   // 127*1024*32 = 4161536 exact
    int kq = gid & 31;
    int b  = (gid >> 5) & 1023;
    int t  = gid >> 15;
    const float* src = padded + (size_t)b*LE + t*E + kq*8;
    float4 v0 = *(const float4*)src;
    float4 v1 = *(const float4*)(src + 4);
    f16x8 v;
    v[0]=(f16)v0.x; v[1]=(f16)v0.y; v[2]=(f16)v0.z; v[3]=(f16)v0.w;
    v[4]=(f16)v1.x; v[5]=(f16)v1.y; v[6]=(f16)v1.z; v[7]=(f16)v1.w;
    int kt = kq >> 3, kb = kq & 7;
    int row = b & 63, mt16 = b >> 6;
    char* dst = (char*)g_Xs + (size_t)((t*16 + mt16)*4 + kt)*8192
              + row*128 + ((kb*16) ^ ((row & 7) << 4));
    *(f16x8*)dst = v;
}

// ---------------------------------------------------------------------------
// init: g_Hh[0] <- hidden image, out row 0 <- one-hot, barrier reset
// ---------------------------------------------------------------------------
__global__ __launch_bounds__(256) void init_kernel(
    const float* __restrict__ hidden, float* __restrict__ out)
{
    int i = blockIdx.x * 256 + threadIdx.x;
    if (i < 8) { g_bars[i].cnt = 0u; g_bars[i].phase = 0u; }
    if (i < B*H) {
        float hv = hidden[i];
        int b = i >> 9, j = i & 511;
        int mt = b >> 6, row = b & 63, kt = j >> 6, kk = j & 63;
        char* dst = (char*)g_Hh + (size_t)(mt*8 + kt)*8192
                  + row*128 + ((kk*2) ^ ((row & 7) << 4));
        *(f16*)dst = (f16)hv;
    }
    if (i < B*E) {
        int b = i >> 8, e = i & 255;
        out[b*LE + e] = (e == 0) ? 1.0f : 0.0f;
    }
}

// ---------------------------------------------------------------------------
// step_all: persistent gates recurrence, 8 INDEPENDENT groups of 32 blocks.
// Group g (= blockIdx&7, same-XCD under round-robin) owns batch rows
// [g*128,+128); block (g,nt) owns gate-cols [nt*64,+64). h exchange is
// group-internal only. B (96 KB) persistent in LDS; X(t+1) prefetched into
// LDS BEFORE the barrier (immune to the exit-acquire invalidate); kt order
// X0..X3,H0..H7 gives a 4-kt runway covering H's post-invalidate L3 latency.
// ---------------------------------------------------------------------------
__global__ __launch_bounds__(256, 1) void step_all()
{
    __shared__ __align__(16) char lds[131072];
    char* Bb = lds;             // 12 x 8192 persistent B images
    char* Ab = lds + 98304;     // 2 x 16384 A dbuf

    const int tid  = threadIdx.x;
    const int lane = tid & 63;
    const int wv   = tid >> 6;          // 0..3 (M quarter)
    const int grp  = blockIdx.x & 7;    // M-group (same XCD under round-robin)
    const int nt   = blockIdx.x >> 3;   // 0..31 (N slice)
    const int l15  = lane & 15;
    const int p    = l15 & 3;           // gate id within 4-lane group
    const int klo  = (lane >> 4) << 4;

    // ---- persistent B load (once): rows (nt&1)*64..+64 of itile nt>>1 ----
    {
        const char* src = (const char*)g_Ws + (size_t)(nt >> 1)*12*16384
                        + (size_t)(nt & 1)*64*128;
        #pragma unroll
        for (int it = 0; it < 24; ++it) {
            int c = wv*24 + it;             // 0..95 chunks of 1KB
            int kt = c >> 3, cc = c & 7;
            __builtin_amdgcn_global_load_lds(
                (gu32*)(src + (size_t)kt*16384 + cc*1024 + lane*16),
                (lu32*)(Bb + c*1024 + lane*16), 16, 0, 0);
        }
    }
    float4 bs4[4];
    #pragma unroll
    for (int n = 0; n < 4; ++n)
        bs4[n] = *(const float4*)&g_bsum[nt*64 + n*16 + (l15 >> 2)*4];

    float creg[2][4];
    #pragma unroll
    for (int m = 0; m < 2; ++m)
        #pragma unroll
        for (int n = 0; n < 4; ++n) creg[m][n] = 0.0f;

    asm volatile("s_waitcnt vmcnt(0)" ::: "memory");
    __syncthreads();

    auto stageA = [&](int t, int kt, int buf) {
        char* dst = Ab + buf*16384;
        #pragma unroll
        for (int it = 0; it < 4; ++it) {
            int c = wv*4 + it;              // 0..15 chunks of 1KB (16 KB)
            int sub = c >> 3, cc = c & 7;   // sub: which 64-row image
            const char* src = (kt < 4)
                ? (const char*)g_Xs + (size_t)((t*16 + grp*2 + sub)*4 + kt)*8192
                : (const char*)g_Hh + (size_t)((t*16 + grp*2 + sub)*8 + (kt-4))*8192;
            __builtin_amdgcn_global_load_lds(
                (gu32*)(src + cc*1024 + lane*16),
                (lu32*)(dst + c*1024 + lane*16), 16, 0, 0);
        }
    };

    // prologue: X(0) kt0/kt1 into both bufs
    stageA(0, 0, 0);
    stageA(0, 1, 1);

    #pragma unroll 1
    for (int t = 0; t < 127; ++t) {
        f32x4 acc[2][4];
        #pragma unroll
        for (int m = 0; m < 2; ++m)
            #pragma unroll
            for (int n = 0; n < 4; ++n) acc[m][n] = (f32x4){0.f,0.f,0.f,0.f};

        #pragma unroll
        for (int kt = 0; kt < 12; ++kt) {
            if (kt < 11) asm volatile("s_waitcnt vmcnt(4)\n\ts_barrier" ::: "memory");
            else         asm volatile("s_waitcnt vmcnt(0)\n\ts_barrier" ::: "memory");
            const char* Ar = Ab + (kt & 1)*16384;
            const char* Br = Bb + kt*8192;
            #pragma unroll
            for (int kkl = 0; kkl < 2; ++kkl) {
                const int kb = kkl*64 + klo;
                f16x8 a[2], b[4];
                #pragma unroll
                for (int m = 0; m < 2; ++m) {
                    int r = wv*32 + m*16 + l15;
                    a[m] = *(const f16x8*)(Ar + (r >> 6)*8192 + (r & 63)*128
                                           + (kb ^ ((r & 7) << 4)));
                }
                #pragma unroll
                for (int n = 0; n < 4; ++n) {
                    int r = n*16 + l15;
                    b[n] = *(const f16x8*)(Br + r*128 + (kb ^ ((r & 7) << 4)));
                }
                #pragma unroll
                for (int m = 0; m < 2; ++m)
                    #pragma unroll
                    for (int n = 0; n < 4; ++n)
                        acc[m][n] = __builtin_amdgcn_mfma_f32_16x16x32_f16(
                            a[m], b[n], acc[m][n], 0, 0, 0);
            }
            asm volatile("s_barrier" ::: "memory");   // reads done before restage
            if (kt < 10) stageA(t, kt + 2, kt & 1);
        }

        // epilogue: 4x4 shfl transpose -> lane owns all 4 gates of one cell;
        // c in regs; h -> g_Hh[t+1] image (flushed by the barrier's release).
        char* hout = (char*)g_Hh + (size_t)(t + 1)*16*8*8192;
        #pragma unroll
        for (int m = 0; m < 2; ++m)
            #pragma unroll
            for (int n = 0; n < 4; ++n) {
                float v0 = acc[m][n][0], v1 = acc[m][n][1];
                float v2 = acc[m][n][2], v3 = acc[m][n][3];
                float s, r;
                s = (p & 1) ? v0 : v1; r = __shfl_xor(s, 1); if (p & 1) v0 = r; else v1 = r;
                s = (p & 1) ? v2 : v3; r = __shfl_xor(s, 1); if (p & 1) v2 = r; else v3 = r;
                s = (p & 2) ? v0 : v2; r = __shfl_xor(s, 2); if (p & 2) v0 = r; else v2 = r;
                s = (p & 2) ? v1 : v3; r = __shfl_xor(s, 2); if (p & 2) v1 = r; else v3 = r;
                float iv = sigm(v0 + bs4[n].x);
                float fv = sigm(v1 + bs4[n].y);
                float gg = tanhf(v2 + bs4[n].z);
                float ov = sigm(v3 + bs4[n].w);
                float cv = fv * creg[m][n] + iv * gg;
                creg[m][n] = cv;
                float hv = ov * tanhf(cv);
                int row = grp*128 + wv*32 + m*16 + ((lane >> 4) << 2) + p;
                int jg  = nt*16 + n*4 + (l15 >> 2);
                char* hd = hout + (size_t)((row >> 6)*8 + (jg >> 6))*8192
                         + (row & 63)*128 + (((jg & 63)*2) ^ (((row & 63) & 7) << 4));
                *(f16*)hd = (f16)hv;
            }

        // X(t+1) prefetch into LDS BEFORE the barrier (h-independent; LDS is
        // immune to the exit-acquire cache invalidate).
        if (t < 126) { stageA(t + 1, 0, 0); stageA(t + 1, 1, 1); }
        asm volatile("s_waitcnt vmcnt(0)" ::: "memory");  // drain h stores + X
        group_barrier(grp, (unsigned)(t + 1));
    }
}

// ---------------------------------------------------------------------------
// mlp_all: batched 3-layer MLP for ALL tokens (round-4 proven structure).
// Block bi: tok = 1 + bi/16 (reads g_Hh[tok]), rows [mt*64,+64), mt = bi&15.
// ---------------------------------------------------------------------------
__global__ __launch_bounds__(256) void mlp_all(
    const float* __restrict__ b1, const float* __restrict__ b2,
    const float* __restrict__ b3, float* __restrict__ out)
{
    __shared__ char lds[65536];
    char* Wb = lds;            // 2 x 16384
    char* Ab = lds + 32768;    // 2 x 8192 (later Z2)
    char* Z1 = lds + 49152;    // 16384
    const int tid  = threadIdx.x;
    const int lane = tid & 63;
    const int w    = tid >> 6;
    const int bi   = blockIdx.x;
    const int tok  = 1 + (bi >> 4);
    const int mt   = bi & 15;
    const char* gH = (const char*)g_Hh + (size_t)(tok*16 + mt)*8*8192;
    float* outb = out + (size_t)(mt*64)*LE + (size_t)tok*E;

    float b1v[2], b2v[2], b3v[2][2];
    #pragma unroll
    for (int n = 0; n < 2; ++n) {
        int col = w*32 + n*16 + (lane & 15);
        b1v[n] = b1[col]; b2v[n] = b2[col];
        b3v[0][n] = b3[col]; b3v[1][n] = b3[128 + col];
    }
    const int kb0_0 = ((lane >> 4) << 4);

    f32x4 acc[4][2];
    #pragma unroll
    for (int m = 0; m < 4; ++m) { acc[m][0] = (f32x4){0,0,0,0}; acc[m][1] = (f32x4){0,0,0,0}; }

    #pragma unroll
    for (int it = 0; it < 2; ++it) {
        int c = w*2 + it;
        __builtin_amdgcn_global_load_lds((gu32*)(gH + c*1024 + lane*16),
                                         (lu32*)(Ab + c*1024 + lane*16), 16, 0, 0);
    }
    #pragma unroll
    for (int it = 0; it < 4; ++it) {
        int c = w*4 + it;
        __builtin_amdgcn_global_load_lds((gu32*)((const char*)g_W1s + c*1024 + lane*16),
                                         (lu32*)(Wb + c*1024 + lane*16), 16, 0, 0);
    }
    __syncthreads();

    for (int kt = 0; kt < 8; ++kt) {
        const int cur = kt & 1;
        if (kt < 7) {
            const char* gA = gH + (size_t)(kt+1)*8192;
            const char* gW = (const char*)g_W1s + (size_t)(kt+1)*16384;
            char* dA = Ab + (cur^1)*8192;
            char* dW = Wb + (cur^1)*16384;
            #pragma unroll
            for (int it = 0; it < 2; ++it) {
                int c = w*2 + it;
                __builtin_amdgcn_global_load_lds((gu32*)(gA + c*1024 + lane*16),
                                                 (lu32*)(dA + c*1024 + lane*16), 16, 0, 0);
            }
            #pragma unroll
            for (int it = 0; it < 4; ++it) {
                int c = w*4 + it;
                __builtin_amdgcn_global_load_lds((gu32*)(gW + c*1024 + lane*16),
                                                 (lu32*)(dW + c*1024 + lane*16), 16, 0, 0);
            }
        }
        const char* Ar = Ab + cur*8192;
        const char* Br = Wb + cur*16384;
        #pragma unroll
        for (int kk = 0; kk < 2; ++kk) {
            const int kb0 = kk*64 + kb0_0;
            f16x8 a[4], b[2];
            #pragma unroll
            for (int m = 0; m < 4; ++m) {
                int ar = m*16 + (lane & 15);
                a[m] = *(const f16x8*)(Ar + ar*128 + (kb0 ^ ((ar & 7) << 4)));
            }
            #pragma unroll
            for (int n = 0; n < 2; ++n) {
                int br = w*32 + n*16 + (lane & 15);
                b[n] = *(const f16x8*)(Br + br*128 + (kb0 ^ ((br & 7) << 4)));
            }
            #pragma unroll
            for (int m = 0; m < 4; ++m)
                #pragma unroll
                for (int n = 0; n < 2; ++n)
                    acc[m][n] = __builtin_amdgcn_mfma_f32_16x16x32_f16(a[m], b[n], acc[m][n], 0, 0, 0);
        }
        __syncthreads();
    }

    #pragma unroll
    for (int m = 0; m < 4; ++m)
        #pragma unroll
        for (int n = 0; n < 2; ++n)
            #pragma unroll
            for (int i = 0; i < 4; ++i) {
                int row = m*16 + ((lane >> 4) << 2) + i;
                int col = w*32 + n*16 + (lane & 15);
                float v = fmaxf(acc[m][n][i] + b1v[n], 0.0f);
                *(f16*)(Z1 + (col >> 6)*8192 + row*128
                        + (((col & 63)*2) ^ ((row & 7) << 4))) = (f16)v;
            }
    __syncthreads();

    #pragma unroll
    for (int it = 0; it < 8; ++it) {
        int c = w*8 + it;
        __builtin_amdgcn_global_load_lds((gu32*)((const char*)g_W2s + c*1024 + lane*16),
                                         (lu32*)(Wb + c*1024 + lane*16), 16, 0, 0);
    }
    __syncthreads();
    #pragma unroll
    for (int m = 0; m < 4; ++m) { acc[m][0] = (f32x4){0,0,0,0}; acc[m][1] = (f32x4){0,0,0,0}; }
    #pragma unroll
    for (int kt = 0; kt < 2; ++kt)
        #pragma unroll
        for (int kk = 0; kk < 2; ++kk) {
            const int kb0 = kk*64 + kb0_0;
            f16x8 a[4], b[2];
            #pragma unroll
            for (int m = 0; m < 4; ++m) {
                int ar = m*16 + (lane & 15);
                a[m] = *(const f16x8*)(Z1 + kt*8192 + ar*128 + (kb0 ^ ((ar & 7) << 4)));
            }
            #pragma unroll
            for (int n = 0; n < 2; ++n) {
                int br = w*32 + n*16 + (lane & 15);
                b[n] = *(const f16x8*)(Wb + kt*16384 + br*128 + (kb0 ^ ((br & 7) << 4)));
            }
            #pragma unroll
            for (int m = 0; m < 4; ++m)
                #pragma unroll
                for (int n = 0; n < 2; ++n)
                    acc[m][n] = __builtin_amdgcn_mfma_f32_16x16x32_f16(a[m], b[n], acc[m][n], 0, 0, 0);
        }
    __syncthreads();

    #pragma unroll
    for (int m = 0; m < 4; ++m)
        #pragma unroll
        for (int n = 0; n < 2; ++n)
            #pragma unroll
            for (int i = 0; i < 4; ++i) {
                int row = m*16 + ((lane >> 4) << 2) + i;
                int col = w*32 + n*16 + (lane & 15);
                float v = fmaxf(acc[m][n][i] + b2v[n], 0.0f);
                *(f16*)(Ab + (col >> 6)*8192 + row*128
                        + (((col & 63)*2) ^ ((row & 7) << 4))) = (f16)v;
            }
    __syncthreads();

    #pragma unroll
    for (int nh = 0; nh < 2; ++nh) {
        #pragma unroll
        for (int it = 0; it < 8; ++it) {
            int c = w*8 + it;
            __builtin_amdgcn_global_load_lds(
                (gu32*)((const char*)g_W3s + (size_t)nh*32768 + c*1024 + lane*16),
                (lu32*)(Wb + c*1024 + lane*16), 16, 0, 0);
        }
        __syncthreads();
        #pragma unroll
        for (int m = 0; m < 4; ++m) { acc[m][0] = (f32x4){0,0,0,0}; acc[m][1] = (f32x4){0,0,0,0}; }
        #pragma unroll
        for (int kt = 0; kt < 2; ++kt)
            #pragma unroll
            for (int kk = 0; kk < 2; ++kk) {
                const int kb0 = kk*64 + kb0_0;
                f16x8 a[4], b[2];
                #pragma unroll
                for (int m = 0; m < 4; ++m) {
                    int ar = m*16 + (lane & 15);
                    a[m] = *(const f16x8*)(Ab + kt*8192 + ar*128 + (kb0 ^ ((ar & 7) << 4)));
                }
                #pragma unroll
                for (int n = 0; n < 2; ++n) {
                    int br = w*32 + n*16 + (lane & 15);
                    b[n] = *(const f16x8*)(Wb + kt*16384 + br*128 + (kb0 ^ ((br & 7) << 4)));
                }
                #pragma unroll
                for (int m = 0; m < 4; ++m)
                    #pragma unroll
                    for (int n = 0; n < 2; ++n)
                        acc[m][n] = __builtin_amdgcn_mfma_f32_16x16x32_f16(a[m], b[n], acc[m][n], 0, 0, 0);
            }
        #pragma unroll
        for (int m = 0; m < 4; ++m)
            #pragma unroll
            for (int n = 0; n < 2; ++n)
                #pragma unroll
                for (int i = 0; i < 4; ++i) {
                    int row = m*16 + ((lane >> 4) << 2) + i;
                    int col = nh*128 + w*32 + n*16 + (lane & 15);
                    outb[(size_t)row*LE + col] = acc[m][n][i] + b3v[nh][n];
                }
        __syncthreads();
    }
}

// ---------------------------------------------------------------------------
extern "C" void kernel_launch(void* const* d_in, const int* in_sizes, int n_in,
                              void* d_out, int out_size, void* d_ws, size_t ws_size,
                              hipStream_t stream) {
    (void)in_sizes; (void)n_in; (void)out_size; (void)d_ws; (void)ws_size;
    const float* hidden = (const float*)d_in[0];
    const float* padded = (const float*)d_in[1];
    const float* W_ih   = (const float*)d_in[2];
    const float* W_hh   = (const float*)d_in[3];
    const float* b_ih   = (const float*)d_in[4];
    const float* b_hh   = (const float*)d_in[5];
    const float* W1     = (const float*)d_in[6];
    const float* b1     = (const float*)d_in[7];
    const float* W2     = (const float*)d_in[8];
    const float* b2     = (const float*)d_in[9];
    const float* W3     = (const float*)d_in[10];
    const float* b3     = (const float*)d_in[11];
    float* out = (float*)d_out;

    conv_w<<<768, 256, 0, stream>>>(W_ih, W_hh, b_ih, b_hh);
    conv_mlp<<<56, 256, 0, stream>>>(W1, W2, W3);
    conv_x<<<16256, 256, 0, stream>>>(padded);
    init_kernel<<<2048, 256, 0, stream>>>(hidden, out);
    step_all<<<256, 256, 0, stream>>>();
    mlp_all<<<2032, 256, 0, stream>>>(b1, b2, b3, out);
}

// Round 9
// 1796.608 us; speedup vs baseline: 3.5009x; 1.0423x over previous
//
#include <hip/hip_runtime.h>
#include <math.h>
#include <stdint.h>

#define B 1024
#define H 512
#define E 256
#define L 128
#define LE (L*E)   // 32768

typedef _Float16 f16;
typedef _Float16 f16x8 __attribute__((ext_vector_type(8)));
typedef float f32x4 __attribute__((ext_vector_type(4)));
typedef const __attribute__((address_space(1))) uint32_t gu32;
typedef __attribute__((address_space(3))) uint32_t lu32;

// ---------------------------------------------------------------------------
// Persistent state in module device globals. Everything rewritten every call.
// ---------------------------------------------------------------------------
__device__ __align__(16) f16 g_Xs[127*16*4*4096];   // X images [t][mt16][kt:4] 64x64
__device__ __align__(16) f16 g_Hh[128*16*8*4096];   // h(t) images, t=0..127 (134 MB)
__device__ __align__(16) f16 g_Ws[16*12*8192];      // gates W' [itile:16][kt:12] 128x64
__device__ __align__(16) f16 g_W1s[8*8192];         // W1' [kt:8] 128x64
__device__ __align__(16) f16 g_W2s[2*8192];         // W2' [kt:2] 128x64
__device__ __align__(16) f16 g_W3s[4*8192];         // W3' [nh:2][kt:2] 128x64
__device__ __align__(16) float g_bsum[2048];        // b_ih+b_hh, n=j*4+g order

// Per-group barrier state: 8 independent 32-block groups, one cacheline each.
struct __align__(128) Bar { unsigned int cnt; unsigned int phase; unsigned int pad[30]; };
__device__ Bar g_bars[8];

// Split barrier (round-8 semantics, validated): arrival at step end releases
// this block's h stores; WAIT is deferred into the next step's X-phase so the
// spin-skew + acquire-invalidate overlap h-independent compute.
__device__ __forceinline__ void bar_arrive(int g, unsigned int target) {
    __syncthreads();
    if (threadIdx.x == 0) {
        unsigned int prev = __hip_atomic_fetch_add(&g_bars[g].cnt, 1u,
                              __ATOMIC_ACQ_REL, __HIP_MEMORY_SCOPE_AGENT);
        if (prev == 31u) {
            __hip_atomic_store(&g_bars[g].cnt, 0u, __ATOMIC_RELAXED, __HIP_MEMORY_SCOPE_AGENT);
            __hip_atomic_store(&g_bars[g].phase, target, __ATOMIC_RELEASE, __HIP_MEMORY_SCOPE_AGENT);
        }
    }
}
__device__ __forceinline__ void bar_wait(int g, unsigned int target) {
    if (threadIdx.x == 0) {
        while (__hip_atomic_load(&g_bars[g].phase, __ATOMIC_RELAXED,
                                 __HIP_MEMORY_SCOPE_AGENT) < target)
            __builtin_amdgcn_s_sleep(1);
        (void)__hip_atomic_load(&g_bars[g].phase, __ATOMIC_ACQUIRE,
                                __HIP_MEMORY_SCOPE_AGENT);
    }
    __syncthreads();
}

__device__ __forceinline__ float fsigm(float x) {
    return __builtin_amdgcn_rcpf(1.0f + __expf(-x));
}
__device__ __forceinline__ float ftanh(float x) {
    return 2.0f * __builtin_amdgcn_rcpf(1.0f + __expf(-2.0f * x)) - 1.0f;
}

// ---------------------------------------------------------------------------
// conv_w: gates W' fp16 tile images (gate-interleaved n=j*4+g) + bias sums
// ---------------------------------------------------------------------------
__global__ __launch_bounds__(256) void conv_w(
    const float* __restrict__ W_ih, const float* __restrict__ W_hh,
    const float* __restrict__ b_ih, const float* __restrict__ b_hh)
{
    int gid = blockIdx.x*256 + threadIdx.x;   // 196608
    int kb  = gid & 7;
    int r1  = gid >> 3;
    int row = r1 & 127;
    int r2  = r1 >> 7;
    int kt  = r2 % 12;
    int nt  = r2 / 12;
    int n = nt*128 + row;
    int g = n & 3, j = n >> 2;
    int wrow = g*512 + j;
    int k = kt*64 + kb*8;
    const float* src = (k < 256) ? (W_ih + wrow*256 + k)
                                 : (W_hh + wrow*512 + (k - 256));
    f16x8 v;
    #pragma unroll
    for (int e = 0; e < 8; ++e) v[e] = (f16)src[e];
    char* dst = (char*)g_Ws + (size_t)(nt*12 + kt)*16384
              + row*128 + ((kb*16) ^ ((row & 7) << 4));
    *(f16x8*)dst = v;
    if (gid < 2048) {
        int gg = gid & 3, jj = gid >> 2;
        g_bsum[gid] = b_ih[gg*512 + jj] + b_hh[gg*512 + jj];
    }
}

// ---------------------------------------------------------------------------
// conv_mlp: W1/W2/W3 fp16 tile images
// ---------------------------------------------------------------------------
__global__ __launch_bounds__(256) void conv_mlp(
    const float* __restrict__ W1, const float* __restrict__ W2,
    const float* __restrict__ W3)
{
    int gid = blockIdx.x*256 + threadIdx.x;   // 14336
    if (gid < 8192) {                         // W1 (128,512) -> 8 tiles
        int s = gid;
        int kb = s & 7, row = (s >> 3) & 127, kt = s >> 10;
        const float* src = W1 + row*512 + kt*64 + kb*8;
        f16x8 v;
        #pragma unroll
        for (int e = 0; e < 8; ++e) v[e] = (f16)src[e];
        char* dst = (char*)g_W1s + (size_t)kt*16384
                  + row*128 + ((kb*16) ^ ((row & 7) << 4));
        *(f16x8*)dst = v;
    } else if (gid < 10240) {                 // W2 (128,128) -> 2 tiles
        int s = gid - 8192;
        int kb = s & 7, row = (s >> 3) & 127, kt = s >> 10;
        const float* src = W2 + row*128 + kt*64 + kb*8;
        f16x8 v;
        #pragma unroll
        for (int e = 0; e < 8; ++e) v[e] = (f16)src[e];
        char* dst = (char*)g_W2s + (size_t)kt*16384
                  + row*128 + ((kb*16) ^ ((row & 7) << 4));
        *(f16x8*)dst = v;
    } else if (gid < 14336) {                 // W3 (256,128) -> [nh:2][kt:2]
        int s = gid - 10240;
        int kb = s & 7, r256 = (s >> 3) & 255, kt = s >> 11;
        int nh = r256 >> 7, row = r256 & 127;
        const float* src = W3 + r256*128 + kt*64 + kb*8;
        f16x8 v;
        #pragma unroll
        for (int e = 0; e < 8; ++e) v[e] = (f16)src[e];
        char* dst = (char*)g_W3s + (size_t)(nh*2 + kt)*16384
                  + row*128 + ((kb*16) ^ ((row & 7) << 4));
        *(f16x8*)dst = v;
    }
}

// ---------------------------------------------------------------------------
// conv_x: X fp16 tile images (coalesced: 32 consecutive lanes = 1 KB)
// ---------------------------------------------------------------------------
__global__ __launch_bounds__(256) void conv_x(const float* __restrict__ padded)
{
    int gid = blockIdx.x*256 + threadIdx.x;   // 127*1024*32 = 4161536 exact
    int kq = gid & 31;
    int b  = (gid >> 5) & 1023;
    int t  = gid >> 15;
    const float* src = padded + (size_t)b*LE + t*E + kq*8;
    float4 v0 = *(const float4*)src;
    float4 v1 = *(const float4*)(src + 4);
    f16x8 v;
    v[0]=(f16)v0.x; v[1]=(f16)v0.y; v[2]=(f16)v0.z; v[3]=(f16)v0.w;
    v[4]=(f16)v1.x; v[5]=(f16)v1.y; v[6]=(f16)v1.z; v[7]=(f16)v1.w;
    int kt = kq >> 3, kb = kq & 7;
    int row = b & 63, mt16 = b >> 6;
    char* dst = (char*)g_Xs + (size_t)((t*16 + mt16)*4 + kt)*8192
              + row*128 + ((kb*16) ^ ((row & 7) << 4));
    *(f16x8*)dst = v;
}

// ---------------------------------------------------------------------------
// init: g_Hh[0] <- hidden image, out row 0 <- one-hot, barrier reset
// ---------------------------------------------------------------------------
__global__ __launch_bounds__(256) void init_kernel(
    const float* __restrict__ hidden, float* __restrict__ out)
{
    int i = blockIdx.x * 256 + threadIdx.x;
    if (i < 8) { g_bars[i].cnt = 0u; g_bars[i].phase = 0u; }
    if (i < B*H) {
        float hv = hidden[i];
        int b = i >> 9, j = i & 511;
        int mt = b >> 6, row = b & 63, kt = j >> 6, kk = j & 63;
        char* dst = (char*)g_Hh + (size_t)(mt*8 + kt)*8192
                  + row*128 + ((kk*2) ^ ((row & 7) << 4));
        *(f16*)dst = (f16)hv;
    }
    if (i < B*E) {
        int b = i >> 8, e = i & 255;
        out[b*LE + e] = (e == 0) ? 1.0f : 0.0f;
    }
}

// ---------------------------------------------------------------------------
// step_all: persistent gates recurrence, 8 groups of 32 blocks. Group
// (blockIdx&7) owns rows [g*128,+128); block owns gate-cols [nt*64,+64).
// B (96 KB) persistent in LDS; 3 A-slots (48 KB) rotate kt%3.
// Per step: compute kt0..3 (X part, h-independent) FIRST, spin+acquire only
// then, stage H depth-3, kt4..11; epilogue -> coalesced h store; arrival.
// vmcnt schedule: kt2->4, kt3->0 (drains X before acquire), else 8.
// ---------------------------------------------------------------------------
__global__ __launch_bounds__(256, 1) void step_all()
{
    __shared__ __align__(16) char lds[147456];
    char* Bb = lds;                                  // 12 x 8192 persistent B
    f16 (*Hs)[16] = (f16 (*)[16])(lds + 131072);     // aliases slot2 post-kt11

    const int tid  = threadIdx.x;
    const int lane = tid & 63;
    const int wv   = tid >> 6;          // 0..3
    const int grp  = blockIdx.x & 7;    // row group (XCD-local heuristic)
    const int nt   = blockIdx.x >> 3;   // 0..31 col slice
    const int l15  = lane & 15;
    const int p    = l15 & 3;
    const int klo  = (lane >> 4) << 4;

    // ---- persistent B load (once) ----
    {
        const char* src = (const char*)g_Ws + (size_t)(nt >> 1)*12*16384
                        + (size_t)(nt & 1)*64*128;
        #pragma unroll
        for (int it = 0; it < 24; ++it) {
            int c = wv*24 + it;
            int kt = c >> 3, cc = c & 7;
            __builtin_amdgcn_global_load_lds(
                (gu32*)(src + (size_t)kt*16384 + cc*1024 + lane*16),
                (lu32*)(Bb + c*1024 + lane*16), 16, 0, 0);
        }
    }
    float4 bs4[4];
    #pragma unroll
    for (int n = 0; n < 4; ++n)
        bs4[n] = *(const float4*)&g_bsum[nt*64 + n*16 + (l15 >> 2)*4];

    float creg[2][4];
    #pragma unroll
    for (int m = 0; m < 2; ++m)
        #pragma unroll
        for (int n = 0; n < 4; ++n) creg[m][n] = 0.0f;

    asm volatile("s_waitcnt vmcnt(0)" ::: "memory");
    __syncthreads();

    auto stageA = [&](int t_, int kt_, int slot) {
        char* dst = lds + 98304 + slot*16384;
        #pragma unroll
        for (int it = 0; it < 4; ++it) {
            int c = wv*4 + it;
            int sub = c >> 3, cc = c & 7;
            const char* src = (kt_ < 4)
                ? (const char*)g_Xs + (size_t)((t_*16 + grp*2 + sub)*4 + kt_)*8192
                : (const char*)g_Hh + (size_t)((t_*16 + grp*2 + sub)*8 + (kt_-4))*8192;
            __builtin_amdgcn_global_load_lds(
                (gu32*)(src + cc*1024 + lane*16),
                (lu32*)(dst + c*1024 + lane*16), 16, 0, 0);
        }
    };

    // prologue: X(0) kt0 -> S0, kt1 -> S1
    stageA(0, 0, 0);
    stageA(0, 1, 1);

    #pragma unroll 1
    for (int t = 0; t < 127; ++t) {
        stageA(t, 2, 2);                       // X kt2 (h-independent)
        f32x4 acc[2][4];
        #pragma unroll
        for (int m = 0; m < 2; ++m)
            #pragma unroll
            for (int n = 0; n < 4; ++n) acc[m][n] = (f32x4){0.f,0.f,0.f,0.f};

        #pragma unroll
        for (int kt = 0; kt < 12; ++kt) {
            if (kt == 2)      asm volatile("s_waitcnt vmcnt(4)\n\ts_barrier" ::: "memory");
            else if (kt == 3) asm volatile("s_waitcnt vmcnt(0)\n\ts_barrier" ::: "memory");
            else              asm volatile("s_waitcnt vmcnt(8)\n\ts_barrier" ::: "memory");
            const char* Ar = lds + 98304 + (kt % 3)*16384;
            const char* Br = Bb + kt*8192;
            #pragma unroll
            for (int kkl = 0; kkl < 2; ++kkl) {
                const int kb = kkl*64 + klo;
                f16x8 a[2], b[4];
                #pragma unroll
                for (int m = 0; m < 2; ++m) {
                    int r = wv*32 + m*16 + l15;
                    a[m] = *(const f16x8*)(Ar + (r >> 6)*8192 + (r & 63)*128
                                           + (kb ^ ((r & 7) << 4)));
                }
                #pragma unroll
                for (int n = 0; n < 4; ++n) {
                    int r = n*16 + l15;
                    b[n] = *(const f16x8*)(Br + r*128 + (kb ^ ((r & 7) << 4)));
                }
                #pragma unroll
                for (int m = 0; m < 2; ++m)
                    #pragma unroll
                    for (int n = 0; n < 4; ++n)
                        acc[m][n] = __builtin_amdgcn_mfma_f32_16x16x32_f16(
                            a[m], b[n], acc[m][n], 0, 0, 0);
            }
            asm volatile("s_barrier" ::: "memory");   // slot reads done
            if (kt == 0) stageA(t, 3, 0);
            if (kt == 3) {
                bar_wait(grp, (unsigned)t);           // h(t) visible; L2 INV here
                stageA(t, 4, 1); stageA(t, 5, 2); stageA(t, 6, 0);
            }
            if (kt == 4) stageA(t, 7, 1);
            if (kt == 5) stageA(t, 8, 2);
            if (kt == 6) stageA(t, 9, 0);
            if (kt == 7) stageA(t, 10, 1);
            if (kt == 8) stageA(t, 11, 2);
            if (kt == 9  && t < 126) stageA(t + 1, 0, 0);
            if (kt == 10 && t < 126) stageA(t + 1, 1, 1);
        }

        // epilogue: 4x4 shfl transpose -> lane holds all 4 gates of one cell;
        // c in regs; h -> LDS tile Hs (aliases S2, free after kt11).
        #pragma unroll
        for (int m = 0; m < 2; ++m)
            #pragma unroll
            for (int n = 0; n < 4; ++n) {
                float v0 = acc[m][n][0], v1 = acc[m][n][1];
                float v2 = acc[m][n][2], v3 = acc[m][n][3];
                float s, r;
                s = (p & 1) ? v0 : v1; r = __shfl_xor(s, 1); if (p & 1) v0 = r; else v1 = r;
                s = (p & 1) ? v2 : v3; r = __shfl_xor(s, 1); if (p & 1) v2 = r; else v3 = r;
                s = (p & 2) ? v0 : v2; r = __shfl_xor(s, 2); if (p & 2) v0 = r; else v2 = r;
                s = (p & 2) ? v1 : v3; r = __shfl_xor(s, 2); if (p & 2) v1 = r; else v3 = r;
                float iv = fsigm(v0 + bs4[n].x);
                float fv = fsigm(v1 + bs4[n].y);
                float gg = ftanh(v2 + bs4[n].z);
                float ov = fsigm(v3 + bs4[n].w);
                float cv = fv * creg[m][n] + iv * gg;
                creg[m][n] = cv;
                float hv = ov * ftanh(cv);
                int rowl = wv*32 + m*16 + ((lane >> 4) << 2) + p;   // 0..127
                int coll = n*4 + (l15 >> 2);                        // 0..15
                Hs[rowl][coll] = (f16)hv;
            }
        __syncthreads();
        // coalesced h store: ONE 16B store per thread (vs 8 scattered 2B)
        {
            char* hout = (char*)g_Hh + (size_t)(t + 1)*16*8*8192;
            int rowl = tid >> 1, half = tid & 1;
            int row = grp*128 + rowl;
            int jg  = nt*16 + half*8;
            f16x8 hv8 = *(const f16x8*)(&Hs[rowl][half*8]);
            char* hd = hout + (size_t)((row >> 6)*8 + (jg >> 6))*8192
                     + (row & 63)*128 + (((jg & 63)*2) ^ ((row & 7) << 4));
            *(f16x8*)hd = hv8;
        }
        asm volatile("s_waitcnt vmcnt(0)" ::: "memory");  // drain h (+X') loads
        bar_arrive(grp, (unsigned)(t + 1));
    }
}

// ---------------------------------------------------------------------------
// mlp_all: batched 3-layer MLP for ALL tokens (round-4 proven structure).
// Block bi: tok = 1 + bi/16 (reads g_Hh[tok]), rows [mt*64,+64), mt = bi&15.
// ---------------------------------------------------------------------------
__global__ __launch_bounds__(256) void mlp_all(
    const float* __restrict__ b1, const float* __restrict__ b2,
    const float* __restrict__ b3, float* __restrict__ out)
{
    __shared__ char lds[65536];
    char* Wb = lds;            // 2 x 16384
    char* Ab = lds + 32768;    // 2 x 8192 (later Z2)
    char* Z1 = lds + 49152;    // 16384
    const int tid  = threadIdx.x;
    const int lane = tid & 63;
    const int w    = tid >> 6;
    const int bi   = blockIdx.x;
    const int tok  = 1 + (bi >> 4);
    const int mt   = bi & 15;
    const char* gH = (const char*)g_Hh + (size_t)(tok*16 + mt)*8*8192;
    float* outb = out + (size_t)(mt*64)*LE + (size_t)tok*E;

    float b1v[2], b2v[2], b3v[2][2];
    #pragma unroll
    for (int n = 0; n < 2; ++n) {
        int col = w*32 + n*16 + (lane & 15);
        b1v[n] = b1[col]; b2v[n] = b2[col];
        b3v[0][n] = b3[col]; b3v[1][n] = b3[128 + col];
    }
    const int kb0_0 = ((lane >> 4) << 4);

    f32x4 acc[4][2];
    #pragma unroll
    for (int m = 0; m < 4; ++m) { acc[m][0] = (f32x4){0,0,0,0}; acc[m][1] = (f32x4){0,0,0,0}; }

    #pragma unroll
    for (int it = 0; it < 2; ++it) {
        int c = w*2 + it;
        __builtin_amdgcn_global_load_lds((gu32*)(gH + c*1024 + lane*16),
                                         (lu32*)(Ab + c*1024 + lane*16), 16, 0, 0);
    }
    #pragma unroll
    for (int it = 0; it < 4; ++it) {
        int c = w*4 + it;
        __builtin_amdgcn_global_load_lds((gu32*)((const char*)g_W1s + c*1024 + lane*16),
                                         (lu32*)(Wb + c*1024 + lane*16), 16, 0, 0);
    }
    __syncthreads();

    for (int kt = 0; kt < 8; ++kt) {
        const int cur = kt & 1;
        if (kt < 7) {
            const char* gA = gH + (size_t)(kt+1)*8192;
            const char* gW = (const char*)g_W1s + (size_t)(kt+1)*16384;
            char* dA = Ab + (cur^1)*8192;
            char* dW = Wb + (cur^1)*16384;
            #pragma unroll
            for (int it = 0; it < 2; ++it) {
                int c = w*2 + it;
                __builtin_amdgcn_global_load_lds((gu32*)(gA + c*1024 + lane*16),
                                                 (lu32*)(dA + c*1024 + lane*16), 16, 0, 0);
            }
            #pragma unroll
            for (int it = 0; it < 4; ++it) {
                int c = w*4 + it;
                __builtin_amdgcn_global_load_lds((gu32*)(gW + c*1024 + lane*16),
                                                 (lu32*)(dW + c*1024 + lane*16), 16, 0, 0);
            }
        }
        const char* Ar = Ab + cur*8192;
        const char* Br = Wb + cur*16384;
        #pragma unroll
        for (int kk = 0; kk < 2; ++kk) {
            const int kb0 = kk*64 + kb0_0;
            f16x8 a[4], b[2];
            #pragma unroll
            for (int m = 0; m < 4; ++m) {
                int ar = m*16 + (lane & 15);
                a[m] = *(const f16x8*)(Ar + ar*128 + (kb0 ^ ((ar & 7) << 4)));
            }
            #pragma unroll
            for (int n = 0; n < 2; ++n) {
                int br = w*32 + n*16 + (lane & 15);
                b[n] = *(const f16x8*)(Br + br*128 + (kb0 ^ ((br & 7) << 4)));
            }
            #pragma unroll
            for (int m = 0; m < 4; ++m)
                #pragma unroll
                for (int n = 0; n < 2; ++n)
                    acc[m][n] = __builtin_amdgcn_mfma_f32_16x16x32_f16(a[m], b[n], acc[m][n], 0, 0, 0);
        }
        __syncthreads();
    }

    #pragma unroll
    for (int m = 0; m < 4; ++m)
        #pragma unroll
        for (int n = 0; n < 2; ++n)
            #pragma unroll
            for (int i = 0; i < 4; ++i) {
                int row = m*16 + ((lane >> 4) << 2) + i;
                int col = w*32 + n*16 + (lane & 15);
                float v = fmaxf(acc[m][n][i] + b1v[n], 0.0f);
                *(f16*)(Z1 + (col >> 6)*8192 + row*128
                        + (((col & 63)*2) ^ ((row & 7) << 4))) = (f16)v;
            }
    __syncthreads();

    #pragma unroll
    for (int it = 0; it < 8; ++it) {
        int c = w*8 + it;
        __builtin_amdgcn_global_load_lds((gu32*)((const char*)g_W2s + c*1024 + lane*16),
                                         (lu32*)(Wb + c*1024 + lane*16), 16, 0, 0);
    }
    __syncthreads();
    #pragma unroll
    for (int m = 0; m < 4; ++m) { acc[m][0] = (f32x4){0,0,0,0}; acc[m][1] = (f32x4){0,0,0,0}; }
    #pragma unroll
    for (int kt = 0; kt < 2; ++kt)
        #pragma unroll
        for (int kk = 0; kk < 2; ++kk) {
            const int kb0 = kk*64 + kb0_0;
            f16x8 a[4], b[2];
            #pragma unroll
            for (int m = 0; m < 4; ++m) {
                int ar = m*16 + (lane & 15);
                a[m] = *(const f16x8*)(Z1 + kt*8192 + ar*128 + (kb0 ^ ((ar & 7) << 4)));
            }
            #pragma unroll
            for (int n = 0; n < 2; ++n) {
                int br = w*32 + n*16 + (lane & 15);
                b[n] = *(const f16x8*)(Wb + kt*16384 + br*128 + (kb0 ^ ((br & 7) << 4)));
            }
            #pragma unroll
            for (int m = 0; m < 4; ++m)
                #pragma unroll
                for (int n = 0; n < 2; ++n)
                    acc[m][n] = __builtin_amdgcn_mfma_f32_16x16x32_f16(a[m], b[n], acc[m][n], 0, 0, 0);
        }
    __syncthreads();

    #pragma unroll
    for (int m = 0; m < 4; ++m)
        #pragma unroll
        for (int n = 0; n < 2; ++n)
            #pragma unroll
            for (int i = 0; i < 4; ++i) {
                int row = m*16 + ((lane >> 4) << 2) + i;
                int col = w*32 + n*16 + (lane & 15);
                float v = fmaxf(acc[m][n][i] + b2v[n], 0.0f);
                *(f16*)(Ab + (col >> 6)*8192 + row*128
                        + (((col & 63)*2) ^ ((row & 7) << 4))) = (f16)v;
            }
    __syncthreads();

    #pragma unroll
    for (int nh = 0; nh < 2; ++nh) {
        #pragma unroll
        for (int it = 0; it < 8; ++it) {
            int c = w*8 + it;
            __builtin_amdgcn_global_load_lds(
                (gu32*)((const char*)g_W3s + (size_t)nh*32768 + c*1024 + lane*16),
                (lu32*)(Wb + c*1024 + lane*16), 16, 0, 0);
        }
        __syncthreads();
        #pragma unroll
        for (int m = 0; m < 4; ++m) { acc[m][0] = (f32x4){0,0,0,0}; acc[m][1] = (f32x4){0,0,0,0}; }
        #pragma unroll
        for (int kt = 0; kt < 2; ++kt)
            #pragma unroll
            for (int kk = 0; kk < 2; ++kk) {
                const int kb0 = kk*64 + kb0_0;
                f16x8 a[4], b[2];
                #pragma unroll
                for (int m = 0; m < 4; ++m) {
                    int ar = m*16 + (lane & 15);
                    a[m] = *(const f16x8*)(Ab + kt*8192 + ar*128 + (kb0 ^ ((ar & 7) << 4)));
                }
                #pragma unroll
                for (int n = 0; n < 2; ++n) {
                    int br = w*32 + n*16 + (lane & 15);
                    b[n] = *(const f16x8*)(Wb + kt*16384 + br*128 + (kb0 ^ ((br & 7) << 4)));
                }
                #pragma unroll
                for (int m = 0; m < 4; ++m)
                    #pragma unroll
                    for (int n = 0; n < 2; ++n)
                        acc[m][n] = __builtin_amdgcn_mfma_f32_16x16x32_f16(a[m], b[n], acc[m][n], 0, 0, 0);
            }
        #pragma unroll
        for (int m = 0; m < 4; ++m)
            #pragma unroll
            for (int n = 0; n < 2; ++n)
                #pragma unroll
                for (int i = 0; i < 4; ++i) {
                    int row = m*16 + ((lane >> 4) << 2) + i;
                    int col = nh*128 + w*32 + n*16 + (lane & 15);
                    outb[(size_t)row*LE + col] = acc[m][n][i] + b3v[nh][n];
                }
        __syncthreads();
    }
}

// ---------------------------------------------------------------------------
extern "C" void kernel_launch(void* const* d_in, const int* in_sizes, int n_in,
                              void* d_out, int out_size, void* d_ws, size_t ws_size,
                              hipStream_t stream) {
    (void)in_sizes; (void)n_in; (void)out_size; (void)d_ws; (void)ws_size;
    const float* hidden = (const float*)d_in[0];
    const float* padded = (const float*)d_in[1];
    const float* W_ih   = (const float*)d_in[2];
    const float* W_hh   = (const float*)d_in[3];
    const float* b_ih   = (const float*)d_in[4];
    const float* b_hh   = (const float*)d_in[5];
    const float* W1     = (const float*)d_in[6];
    const float* b1     = (const float*)d_in[7];
    const float* W2     = (const float*)d_in[8];
    const float* b2     = (const float*)d_in[9];
    const float* W3     = (const float*)d_in[10];
    const float* b3     = (const float*)d_in[11];
    float* out = (float*)d_out;

    conv_w<<<768, 256, 0, stream>>>(W_ih, W_hh, b_ih, b_hh);
    conv_mlp<<<56, 256, 0, stream>>>(W1, W2, W3);
    conv_x<<<16256, 256, 0, stream>>>(padded);
    init_kernel<<<2048, 256, 0, stream>>>(hidden, out);
    step_all<<<256, 256, 0, stream>>>();
    mlp_all<<<2032, 256, 0, stream>>>(b1, b2, b3, out);
}